// Round 1
// baseline (1048.012 us; speedup 1.0000x reference)
//
#include <hip/hip_runtime.h>
#include <math.h>

#define LN_TOK 4096
#define NB 2
#define NROWS (NB * LN_TOK)          // 8192
#define DMODEL 256
#define DINNER 1024
#define NHEADS 8
#define GNN 128
#define DPROJ 2312
#define EPSF 1e-5f
#define NCHUNK 32
#define CHUNK 128

__device__ __forceinline__ float sigmoidf_(float v) { return 1.f / (1.f + __expf(-v)); }
__device__ __forceinline__ float siluf_(float v)    { return v / (1.f + __expf(-v)); }
__device__ __forceinline__ float softplusf_(float v){ return v > 20.f ? v : log1pf(__expf(v)); }

// ---------------- LayerNorm over DMODEL=256, one block per row ----------------
__global__ void k_ln(const float* __restrict__ u, const float* __restrict__ gam,
                     const float* __restrict__ bet, float* __restrict__ xn) {
    int row = blockIdx.x;
    int tid = threadIdx.x;
    float v = u[(size_t)row * DMODEL + tid];
    __shared__ float s1[256], s2[256];
    s1[tid] = v; s2[tid] = v * v;
    __syncthreads();
    for (int off = 128; off > 0; off >>= 1) {
        if (tid < off) { s1[tid] += s1[tid + off]; s2[tid] += s2[tid + off]; }
        __syncthreads();
    }
    float mean = s1[0] * (1.f / DMODEL);
    float var  = s2[0] * (1.f / DMODEL) - mean * mean;
    float r = rsqrtf(var + EPSF);
    xn[(size_t)row * DMODEL + tid] = (v - mean) * r * gam[tid] + bet[tid];
}

// ---------------- Generic fp32 tiled GEMM: C = A(MxK) @ B(KxN) [+ addC] ------
template <int BM, int BN, int BK, int TM, int TN>
__global__ void k_sgemm(const float* __restrict__ A, const float* __restrict__ Bm,
                        float* __restrict__ C, int M, int N, int K,
                        const float* __restrict__ addC) {
    __shared__ float As[BK][BM + 1];
    __shared__ float Bs[BK][BN + 1];
    constexpr int THREADS = (BM / TM) * (BN / TN);
    const int tid = threadIdx.x;
    const int tcols = BN / TN;
    const int tr = tid / tcols, tc = tid % tcols;
    const int row0 = blockIdx.y * BM, col0 = blockIdx.x * BN;
    float acc[TM][TN];
#pragma unroll
    for (int i = 0; i < TM; i++)
#pragma unroll
        for (int j = 0; j < TN; j++) acc[i][j] = 0.f;

    for (int k0 = 0; k0 < K; k0 += BK) {
        for (int i = tid; i < BM * BK; i += THREADS) {
            int m = i / BK, kk = i % BK;
            int r = row0 + m;
            As[kk][m] = (r < M) ? A[(size_t)r * K + k0 + kk] : 0.f;
        }
        for (int i = tid; i < BK * BN; i += THREADS) {
            int kk = i / BN, n = i % BN;
            int cc = col0 + n;
            Bs[kk][n] = (cc < N) ? Bm[(size_t)(k0 + kk) * N + cc] : 0.f;
        }
        __syncthreads();
#pragma unroll
        for (int kk = 0; kk < BK; kk++) {
            float a[TM], b[TN];
#pragma unroll
            for (int i = 0; i < TM; i++) a[i] = As[kk][tr * TM + i];
#pragma unroll
            for (int j = 0; j < TN; j++) b[j] = Bs[kk][tc * TN + j];
#pragma unroll
            for (int i = 0; i < TM; i++)
#pragma unroll
                for (int j = 0; j < TN; j++) acc[i][j] += a[i] * b[j];
        }
        __syncthreads();
    }
#pragma unroll
    for (int i = 0; i < TM; i++) {
        int r = row0 + tr * TM + i;
        if (r >= M) continue;
#pragma unroll
        for (int j = 0; j < TN; j++) {
            int cc = col0 + tc * TN + j;
            if (cc >= N) continue;
            float v = acc[i][j];
            if (addC) v += addC[(size_t)r * N + cc];
            C[(size_t)r * N + cc] = v;
        }
    }
}

// ---------------- conv(K=4, causal) + SiLU + splits + dt/A prep --------------
// one block per (b,t); 256 threads cover 1280 channels (5 each, stride 256)
__global__ void k_conv(const float* __restrict__ zx, const float* __restrict__ cw,
                       const float* __restrict__ cb, const float* __restrict__ dt_bias,
                       const float* __restrict__ A_log,
                       float* __restrict__ xsh, float* __restrict__ Bsh,
                       float* __restrict__ Csh, float* __restrict__ dtp,
                       float* __restrict__ laa) {
    int bt = blockIdx.x;
    int b = bt / LN_TOK, t = bt % LN_TOK;
    int tid = threadIdx.x;
    __shared__ float sv[1280];
#pragma unroll
    for (int i = 0; i < 5; i++) {
        int c = tid + i * 256;
        float acc = cb[c];
#pragma unroll
        for (int k = 0; k < 4; k++) {
            int tt = t + k - 3;
            if (tt >= 0)
                acc += zx[((size_t)(b * LN_TOK + tt)) * DPROJ + DINNER + c] * cw[c * 4 + k];
        }
        sv[c] = siluf_(acc);
    }
    __syncthreads();
    size_t rowp = (size_t)(b * LN_TOK + t) * GNN;
    if (tid < 128) {
        float s = 0.f;
#pragma unroll
        for (int h = 0; h < NHEADS; h++) s += sv[h * 128 + tid];
        xsh[rowp + tid] = s * 0.125f;
    } else {
        int n = tid - 128;
        Bsh[rowp + n] = sv[1024 + n];
        Csh[rowp + n] = sv[1152 + n];
    }
    if (tid < NHEADS) {
        int h = tid;
        float dtv = zx[(size_t)(b * LN_TOK + t) * DPROJ + 2304 + h] + dt_bias[h];
        float dp = softplusf_(dtv);
        size_t idx = ((size_t)(b * NHEADS + h)) * LN_TOK + t;
        dtp[idx] = dp;
        laa[idx] = -__expf(A_log[h]) * dp;
    }
}

// ---------------- per-chunk inclusive prefix sum of log-decay ----------------
__global__ void k_prefix(const float* __restrict__ laa, float* __restrict__ gcum) {
    int blk = blockIdx.x;           // bh*32 + c
    int bh = blk / NCHUNK, c = blk % NCHUNK;
    int tid = threadIdx.x;          // 128
    __shared__ float s[128];
    size_t base = (size_t)bh * LN_TOK + c * CHUNK;
    s[tid] = laa[base + tid];
    __syncthreads();
    for (int off = 1; off < 128; off <<= 1) {
        float v = (tid >= off) ? s[tid - off] : 0.f;
        __syncthreads();
        s[tid] += v;
        __syncthreads();
    }
    gcum[base + tid] = s[tid];
}

// ---------------- kernel A: masked decay matrix M_T[s][t] per (b,h,c) --------
__global__ void k_chunkM(const float* __restrict__ Bsh, const float* __restrict__ Csh,
                         const float* __restrict__ Bscale, const float* __restrict__ gcum,
                         const float* __restrict__ dtp, float* __restrict__ MT) {
    int blk = blockIdx.x;           // b*256 + h*32 + c
    int c = blk & 31, h = (blk >> 5) & 7, b = blk >> 8;
    int t0 = c * CHUNK;
    int tid = threadIdx.x;
    int tr = tid >> 4, tc = tid & 15;
    __shared__ float Bhs[16][129];
    __shared__ float Cs[16][129];
    __shared__ float g[128], dts[128];
    size_t bhbase = (size_t)(b * NHEADS + h) * LN_TOK + t0;
    if (tid < 128) { g[tid] = gcum[bhbase + tid]; dts[tid] = dtp[bhbase + tid]; }
    float acc[8][8];
#pragma unroll
    for (int i = 0; i < 8; i++)
#pragma unroll
        for (int j = 0; j < 8; j++) acc[i][j] = 0.f;
    size_t rowbase = (size_t)(b * LN_TOK + t0);
    for (int n0 = 0; n0 < 128; n0 += 16) {
        for (int i = tid; i < 128 * 16; i += 256) {
            int s = i >> 4, kk = i & 15;
            Bhs[kk][s] = Bsh[(rowbase + s) * GNN + n0 + kk] * Bscale[h * GNN + n0 + kk];
            Cs[kk][s]  = Csh[(rowbase + s) * GNN + n0 + kk];
        }
        __syncthreads();
#pragma unroll
        for (int kk = 0; kk < 16; kk++) {
            float a[8], bb[8];
#pragma unroll
            for (int i = 0; i < 8; i++) a[i] = Bhs[kk][tr * 8 + i];
#pragma unroll
            for (int j = 0; j < 8; j++) bb[j] = Cs[kk][tc * 8 + j];
#pragma unroll
            for (int i = 0; i < 8; i++)
#pragma unroll
                for (int j = 0; j < 8; j++) acc[i][j] += a[i] * bb[j];
        }
        __syncthreads();
    }
    size_t mbase = (size_t)blk * (CHUNK * CHUNK);
#pragma unroll
    for (int i = 0; i < 8; i++) {
        int s = tr * 8 + i;
#pragma unroll
        for (int j = 0; j < 8; j++) {
            int t = tc * 8 + j;
            float v = (s <= t) ? acc[i][j] * __expf(g[t] - g[s]) * dts[s] : 0.f;
            MT[mbase + (size_t)s * CHUNK + t] = v;
        }
    }
}

// ---------------- kernel B: per-chunk local state Sloc[n][p] -----------------
__global__ void k_chunkS(const float* __restrict__ Bsh, const float* __restrict__ xsh,
                         const float* __restrict__ Bscale, const float* __restrict__ gcum,
                         const float* __restrict__ dtp, float* __restrict__ states) {
    int blk = blockIdx.x;
    int c = blk & 31, h = (blk >> 5) & 7, b = blk >> 8;
    int t0 = c * CHUNK;
    int tid = threadIdx.x;
    int tr = tid >> 4, tc = tid & 15;
    __shared__ float Bt[16][129];
    __shared__ float Xt[16][129];
    __shared__ float esc[128];
    size_t bhbase = (size_t)(b * NHEADS + h) * LN_TOK + t0;
    if (tid < 128) {
        float gl = gcum[bhbase + 127];
        esc[tid] = __expf(gl - gcum[bhbase + tid]) * dtp[bhbase + tid];
    }
    __syncthreads();
    float acc[8][8];
#pragma unroll
    for (int i = 0; i < 8; i++)
#pragma unroll
        for (int j = 0; j < 8; j++) acc[i][j] = 0.f;
    size_t rowbase = (size_t)(b * LN_TOK + t0);
    for (int s0 = 0; s0 < 128; s0 += 16) {
        for (int i = tid; i < 16 * 128; i += 256) {
            int ss = i >> 7, n = i & 127;
            Bt[ss][n] = Bsh[(rowbase + s0 + ss) * GNN + n] * Bscale[h * GNN + n] * esc[s0 + ss];
            Xt[ss][n] = xsh[(rowbase + s0 + ss) * GNN + n];
        }
        __syncthreads();
#pragma unroll
        for (int kk = 0; kk < 16; kk++) {
            float a[8], bb[8];
#pragma unroll
            for (int i = 0; i < 8; i++) a[i] = Bt[kk][tr * 8 + i];
#pragma unroll
            for (int j = 0; j < 8; j++) bb[j] = Xt[kk][tc * 8 + j];
#pragma unroll
            for (int i = 0; i < 8; i++)
#pragma unroll
                for (int j = 0; j < 8; j++) acc[i][j] += a[i] * bb[j];
        }
        __syncthreads();
    }
    size_t sbase = (size_t)blk * (GNN * CHUNK);
#pragma unroll
    for (int i = 0; i < 8; i++)
#pragma unroll
        for (int j = 0; j < 8; j++)
            states[sbase + (size_t)(tr * 8 + i) * CHUNK + tc * 8 + j] = acc[i][j];
}

// ---------------- inter-chunk scan (in-place: Sloc -> chunk-start S0) --------
__global__ void k_scan(float* __restrict__ states, const float* __restrict__ gcum) {
    int idx = blockIdx.x * 256 + threadIdx.x;   // 2*8*16384
    int bh = idx >> 14;
    int np = idx & 16383;
    float run = 0.f;
    size_t base = (size_t)bh * NCHUNK * 16384 + np;
    size_t gb = (size_t)bh * LN_TOK;
    for (int c = 0; c < NCHUNK; c++) {
        float G = __expf(gcum[gb + c * CHUNK + 127]);
        float l = states[base + (size_t)c * 16384];
        states[base + (size_t)c * 16384] = run;
        run = G * run + l;
    }
}

// ---------------- kernel C: Y = [C'|M] @ [S0;X] + D*x ------------------------
__global__ void k_chunkY(const float* __restrict__ Csh, const float* __restrict__ xsh,
                         const float* __restrict__ states, const float* __restrict__ MT,
                         const float* __restrict__ gcum, const float* __restrict__ Dp,
                         float* __restrict__ y) {
    int blk = blockIdx.x;
    int c = blk & 31, h = (blk >> 5) & 7, b = blk >> 8;
    int t0 = c * CHUNK;
    int tid = threadIdx.x;
    int tr = tid >> 4, tc = tid & 15;
    __shared__ float As[16][129];
    __shared__ float Bs[16][129];
    __shared__ float eg[128];
    size_t bhbase = (size_t)(b * NHEADS + h) * LN_TOK + t0;
    if (tid < 128) eg[tid] = __expf(gcum[bhbase + tid]);
    __syncthreads();
    float acc[8][8];
#pragma unroll
    for (int i = 0; i < 8; i++)
#pragma unroll
        for (int j = 0; j < 8; j++) acc[i][j] = 0.f;
    size_t rowbase = (size_t)(b * LN_TOK + t0);
    size_t sbase = (size_t)blk * 16384;
    size_t mbase = (size_t)blk * 16384;
    for (int k0 = 0; k0 < 256; k0 += 16) {
        if (k0 < 128) {
            for (int i = tid; i < 128 * 16; i += 256) {
                int t = i >> 4, kk = i & 15;
                As[kk][t] = Csh[(rowbase + t) * GNN + k0 + kk] * eg[t];
            }
            for (int i = tid; i < 16 * 128; i += 256) {
                int kk = i >> 7, p = i & 127;
                Bs[kk][p] = states[sbase + (size_t)(k0 + kk) * CHUNK + p];
            }
        } else {
            int s0 = k0 - 128;
            for (int i = tid; i < 16 * 128; i += 256) {
                int kk = i >> 7, t = i & 127;
                As[kk][t] = MT[mbase + (size_t)(s0 + kk) * CHUNK + t];
            }
            for (int i = tid; i < 16 * 128; i += 256) {
                int kk = i >> 7, p = i & 127;
                Bs[kk][p] = xsh[(rowbase + s0 + kk) * GNN + p];
            }
        }
        __syncthreads();
#pragma unroll
        for (int kk = 0; kk < 16; kk++) {
            float a[8], bb[8];
#pragma unroll
            for (int i = 0; i < 8; i++) a[i] = As[kk][tr * 8 + i];
#pragma unroll
            for (int j = 0; j < 8; j++) bb[j] = Bs[kk][tc * 8 + j];
#pragma unroll
            for (int i = 0; i < 8; i++)
#pragma unroll
                for (int j = 0; j < 8; j++) acc[i][j] += a[i] * bb[j];
        }
        __syncthreads();
    }
    float D = Dp[h];
#pragma unroll
    for (int i = 0; i < 8; i++) {
        int t = tr * 8 + i;
#pragma unroll
        for (int j = 0; j < 8; j++) {
            int p = tc * 8 + j;
            float v = acc[i][j] + D * xsh[(rowbase + t) * GNN + p];
            y[(rowbase + t) * (size_t)DINNER + h * 128 + p] = v;
        }
    }
}

// ---------------- gating + RMSNorm (in-place on y) ---------------------------
__global__ void k_gate(float* __restrict__ y, const float* __restrict__ zx,
                       const float* __restrict__ rw) {
    int row = blockIdx.x;
    int tid = threadIdx.x;
    size_t yb = (size_t)row * DINNER;
    size_t zb = (size_t)row * DPROJ;
    float yg[4];
    float ss = 0.f;
#pragma unroll
    for (int q = 0; q < 4; q++) {
        int k = tid * 4 + q;
        float z = zx[zb + k];
        float v = y[yb + k] * z * sigmoidf_(z);
        yg[q] = v;
        ss += v * v;
    }
    __shared__ float red[256];
    red[tid] = ss;
    __syncthreads();
    for (int off = 128; off > 0; off >>= 1) {
        if (tid < off) red[tid] += red[tid + off];
        __syncthreads();
    }
    float scale = rsqrtf(red[0] * (1.f / DINNER) + EPSF);
#pragma unroll
    for (int q = 0; q < 4; q++) {
        int k = tid * 4 + q;
        y[yb + k] = yg[q] * scale * rw[k];
    }
}

extern "C" void kernel_launch(void* const* d_in, const int* in_sizes, int n_in,
                              void* d_out, int out_size, void* d_ws, size_t ws_size,
                              hipStream_t stream) {
    (void)in_sizes; (void)n_in; (void)out_size; (void)ws_size;
    const float* u        = (const float*)d_in[0];
    const float* ln_gamma = (const float*)d_in[1];
    const float* ln_beta  = (const float*)d_in[2];
    const float* W_in     = (const float*)d_in[3];
    const float* conv_w   = (const float*)d_in[4];
    const float* conv_b   = (const float*)d_in[5];
    const float* dt_bias  = (const float*)d_in[6];
    const float* A_log    = (const float*)d_in[7];
    const float* D_param  = (const float*)d_in[8];
    const float* B_scale  = (const float*)d_in[9];
    const float* rms_w    = (const float*)d_in[10];
    const float* W_out    = (const float*)d_in[11];
    float* out = (float*)d_out;

    float* ws = (float*)d_ws;
    // workspace layout (floats)
    float* xn   = ws;                          // 2,097,152
    float* zx   = xn + 2097152;                // 18,939,904
    float* xsh  = zx + 18939904;               // 1,048,576
    float* Bsh  = xsh + 1048576;               // 1,048,576
    float* Csh  = Bsh + 1048576;               // 1,048,576
    float* dtp  = Csh + 1048576;               // 65,536
    float* laa  = dtp + 65536;                 // 65,536
    float* gcum = laa + 65536;                 // 65,536
    float* MT   = gcum + 65536;                // 8,388,608
    float* st   = MT + 8388608;                // 8,388,608
    float* ybuf = st + 8388608;                // 8,388,608  (total ~198 MB)

    k_ln<<<NROWS, 256, 0, stream>>>(u, ln_gamma, ln_beta, xn);

    dim3 g2((DPROJ + 127) / 128, NROWS / 128);
    k_sgemm<128, 128, 16, 8, 8><<<g2, 256, 0, stream>>>(xn, W_in, zx, NROWS, DPROJ, DMODEL, nullptr);

    k_conv<<<NROWS, 256, 0, stream>>>(zx, conv_w, conv_b, dt_bias, A_log, xsh, Bsh, Csh, dtp, laa);

    k_prefix<<<NB * NHEADS * NCHUNK, 128, 0, stream>>>(laa, gcum);

    k_chunkM<<<NB * NHEADS * NCHUNK, 256, 0, stream>>>(Bsh, Csh, B_scale, gcum, dtp, MT);

    k_chunkS<<<NB * NHEADS * NCHUNK, 256, 0, stream>>>(Bsh, xsh, B_scale, gcum, dtp, st);

    k_scan<<<(NB * NHEADS * 16384) / 256, 256, 0, stream>>>(st, gcum);

    k_chunkY<<<NB * NHEADS * NCHUNK, 256, 0, stream>>>(Csh, xsh, st, MT, gcum, D_param, ybuf);

    k_gate<<<NROWS, 256, 0, stream>>>(ybuf, zx, rms_w);

    dim3 ge(DMODEL / 64, NROWS / 64);
    k_sgemm<64, 64, 16, 4, 4><<<ge, 256, 0, stream>>>(ybuf, W_out, out, NROWS, DMODEL, DINNER, u);
}

// Round 2
// 333.675 us; speedup vs baseline: 3.1408x; 3.1408x over previous
//
#include <hip/hip_runtime.h>
#include <math.h>

#define LN_TOK 4096
#define NB 2
#define NROWS (NB * LN_TOK)          // 8192
#define DMODEL 256
#define DINNER 1024
#define NHEADS 8
#define GNN 128
#define DPROJ 2312
#define ZSTRIDE 2432                 // padded in-proj N (19*128)
#define EPSF 1e-5f
#define NCHUNK 32
#define CHUNK 128
#define GPAD 72                      // LDS row stride in bf16 elems (144 B)

typedef unsigned short u16;
typedef unsigned int u32;
typedef __attribute__((ext_vector_type(8))) short shortx8;
typedef __attribute__((ext_vector_type(4))) float floatx4;

__device__ __forceinline__ float sigmoidf_(float v) { return 1.f / (1.f + __expf(-v)); }
__device__ __forceinline__ float siluf_(float v)    { return v / (1.f + __expf(-v)); }
__device__ __forceinline__ float softplusf_(float v){ return v > 20.f ? v : log1pf(__expf(v)); }
__device__ __forceinline__ float b2f(u16 h) { return __uint_as_float(((u32)h) << 16); }
__device__ __forceinline__ u16 f2b(float f) {
    u32 u = __float_as_uint(f);
    u32 r = (u + 0x7fffu + ((u >> 16) & 1u)) >> 16;
    return (u16)r;
}

// ---------------- LayerNorm -> bf16 xn ----------------
__global__ void k_ln(const float* __restrict__ u, const float* __restrict__ gam,
                     const float* __restrict__ bet, u16* __restrict__ xn) {
    int row = blockIdx.x;
    int tid = threadIdx.x;
    float v = u[(size_t)row * DMODEL + tid];
    __shared__ float s1[256], s2[256];
    s1[tid] = v; s2[tid] = v * v;
    __syncthreads();
    for (int off = 128; off > 0; off >>= 1) {
        if (tid < off) { s1[tid] += s1[tid + off]; s2[tid] += s2[tid + off]; }
        __syncthreads();
    }
    float mean = s1[0] * (1.f / DMODEL);
    float var  = s2[0] * (1.f / DMODEL) - mean * mean;
    float r = rsqrtf(var + EPSF);
    xn[(size_t)row * DMODEL + tid] = f2b((v - mean) * r * gam[tid] + bet[tid]);
}

// ---------------- transpose-cast fp32 [R][C] -> bf16 [Cp][R], zero pad rows --
__global__ void k_tcast(const float* __restrict__ in, u16* __restrict__ out,
                        int R, int C, int Cp) {
    __shared__ float tile[64][65];
    int c0 = blockIdx.x * 64, r0 = blockIdx.y * 64;
    int tx = threadIdx.x & 63, ty = threadIdx.x >> 6;
    for (int rr = ty; rr < 64; rr += 4) {
        int r = r0 + rr, c = c0 + tx;
        tile[rr][tx] = (r < R && c < C) ? in[(size_t)r * C + c] : 0.f;
    }
    __syncthreads();
    for (int cc = ty; cc < 64; cc += 4) {
        int c = c0 + cc, r = r0 + tx;
        if (c < Cp && r < R) out[(size_t)c * R + r] = f2b(tile[tx][cc]);
    }
}

// ---------------- bf16 transpose: xsh [b*4096+t][128] -> XT [b*128+p][4096] --
__global__ void k_tbf(const u16* __restrict__ in, u16* __restrict__ out) {
    __shared__ u16 tile[64][65];
    int b = blockIdx.z;
    int p0 = blockIdx.x * 64, t0 = blockIdx.y * 64;
    int tx = threadIdx.x & 63, ty = threadIdx.x >> 6;
    for (int tt = ty; tt < 64; tt += 4)
        tile[tt][tx] = in[((size_t)(b * LN_TOK + t0 + tt)) * GNN + p0 + tx];
    __syncthreads();
    for (int pp = ty; pp < 64; pp += 4)
        out[((size_t)(b * GNN + p0 + pp)) * LN_TOK + t0 + tx] = tile[tx][pp];
}

// ---------------- bf16 MFMA GEMM: C = A(MxK) @ Bt(NxK)^T [+addC] ------------
// grid.x = N/128, grid.y = M/128, 256 threads = 4 waves (2x2), 64x64/wave
__global__ __launch_bounds__(256) void k_gemm(const u16* __restrict__ A,
                                              const u16* __restrict__ Bt,
                                              float* __restrict__ C,
                                              int K, int ldc,
                                              const float* __restrict__ addC) {
    __shared__ u16 As[128 * GPAD];
    __shared__ u16 Bs[128 * GPAD];
    int tid = threadIdx.x;
    int wave = tid >> 6, lane = tid & 63;
    int wm = wave >> 1, wn = wave & 1;
    int quad = lane >> 4, l16 = lane & 15;
    int m0 = blockIdx.y * 128, n0 = blockIdx.x * 128;
    floatx4 acc[4][4] = {};
    for (int k0 = 0; k0 < K; k0 += 64) {
#pragma unroll
        for (int p = 0; p < 4; p++) {
            int i = p * 256 + tid;
            int row = i >> 3, kk = (i & 7) << 3;
            *(int4*)&As[row * GPAD + kk] = *(const int4*)&A[(size_t)(m0 + row) * K + k0 + kk];
            *(int4*)&Bs[row * GPAD + kk] = *(const int4*)&Bt[(size_t)(n0 + row) * K + k0 + kk];
        }
        __syncthreads();
#pragma unroll
        for (int ks = 0; ks < 64; ks += 32) {
            shortx8 af[4], bfr[4];
#pragma unroll
            for (int i = 0; i < 4; i++)
                af[i] = *(shortx8*)&As[(wm * 64 + i * 16 + l16) * GPAD + ks + (quad << 3)];
#pragma unroll
            for (int j = 0; j < 4; j++)
                bfr[j] = *(shortx8*)&Bs[(wn * 64 + j * 16 + l16) * GPAD + ks + (quad << 3)];
#pragma unroll
            for (int i = 0; i < 4; i++)
#pragma unroll
                for (int j = 0; j < 4; j++)
                    acc[i][j] = __builtin_amdgcn_mfma_f32_16x16x32_bf16(af[i], bfr[j], acc[i][j], 0, 0, 0);
        }
        __syncthreads();
    }
#pragma unroll
    for (int i = 0; i < 4; i++) {
        int row = m0 + wm * 64 + i * 16 + quad * 4;
#pragma unroll
        for (int j = 0; j < 4; j++) {
            int col = n0 + wn * 64 + j * 16 + l16;
#pragma unroll
            for (int r = 0; r < 4; r++) {
                size_t idx = (size_t)(row + r) * ldc + col;
                float v = acc[i][j][r];
                if (addC) v += addC[idx];
                C[idx] = v;
            }
        }
    }
}

// ---------------- conv(K=4, causal) + SiLU + splits + dt/A prep --------------
__global__ void k_conv(const float* __restrict__ zx, const float* __restrict__ cw,
                       const float* __restrict__ cb, const float* __restrict__ dt_bias,
                       const float* __restrict__ A_log,
                       u16* __restrict__ xsh, u16* __restrict__ Bsh,
                       u16* __restrict__ Csh, float* __restrict__ dtp,
                       float* __restrict__ laa) {
    int bt = blockIdx.x;
    int b = bt / LN_TOK, t = bt % LN_TOK;
    int tid = threadIdx.x;
    __shared__ float sv[1280];
#pragma unroll
    for (int i = 0; i < 5; i++) {
        int c = tid + i * 256;
        float acc = cb[c];
#pragma unroll
        for (int k = 0; k < 4; k++) {
            int tt = t + k - 3;
            if (tt >= 0)
                acc += zx[((size_t)(b * LN_TOK + tt)) * ZSTRIDE + DINNER + c] * cw[c * 4 + k];
        }
        sv[c] = siluf_(acc);
    }
    __syncthreads();
    size_t rowp = (size_t)(b * LN_TOK + t) * GNN;
    if (tid < 128) {
        float s = 0.f;
#pragma unroll
        for (int h = 0; h < NHEADS; h++) s += sv[h * 128 + tid];
        xsh[rowp + tid] = f2b(s * 0.125f);
    } else {
        int n = tid - 128;
        Bsh[rowp + n] = f2b(sv[1024 + n]);
        Csh[rowp + n] = f2b(sv[1152 + n]);
    }
    if (tid < NHEADS) {
        int h = tid;
        float dtv = zx[(size_t)(b * LN_TOK + t) * ZSTRIDE + 2304 + h] + dt_bias[h];
        float dp = softplusf_(dtv);
        size_t idx = ((size_t)(b * NHEADS + h)) * LN_TOK + t;
        dtp[idx] = dp;
        laa[idx] = -__expf(A_log[h]) * dp;
    }
}

// ---------------- Bh[b][h][t][n] = Bsh[b][t][n] * scale[h][n] (bf16) ---------
__global__ void k_bh(const u16* __restrict__ Bsh, const float* __restrict__ scale,
                     u16* __restrict__ Bh) {
    int row = blockIdx.x;                // b*4096+t
    int b = row >> 12, t = row & 4095;
    int tid = threadIdx.x;               // 128
    float v = b2f(Bsh[(size_t)row * GNN + tid]);
#pragma unroll
    for (int h = 0; h < NHEADS; h++)
        Bh[((size_t)((b * NHEADS + h) * LN_TOK + t)) * GNN + tid] = f2b(v * scale[h * GNN + tid]);
}

// ---------------- per-chunk inclusive prefix sum of log-decay ----------------
__global__ void k_prefix(const float* __restrict__ laa, float* __restrict__ gcum) {
    int blk = blockIdx.x;
    int bh = blk / NCHUNK, c = blk % NCHUNK;
    int tid = threadIdx.x;
    __shared__ float s[128];
    size_t base = (size_t)bh * LN_TOK + c * CHUNK;
    s[tid] = laa[base + tid];
    __syncthreads();
    for (int off = 1; off < 128; off <<= 1) {
        float v = (tid >= off) ? s[tid - off] : 0.f;
        __syncthreads();
        s[tid] += v;
        __syncthreads();
    }
    gcum[base + tid] = s[tid];
}

// ---------------- chunkM (MFMA): Mb[t][s] = mask*exp(g_t-g_s)*dt_s*(Bh_s.C_t)
__global__ __launch_bounds__(256) void k_chunkM(const u16* __restrict__ Bh,
                                                const u16* __restrict__ Csh,
                                                const float* __restrict__ gcum,
                                                const float* __restrict__ dtp,
                                                u16* __restrict__ Mb) {
    int blk = blockIdx.x;
    int c = blk & 31, h = (blk >> 5) & 7, b = blk >> 8;
    int t0 = c * CHUNK;
    __shared__ u16 As[128 * GPAD];
    __shared__ u16 Bs[128 * GPAD];
    __shared__ float g[128], dts[128];
    int tid = threadIdx.x;
    int wave = tid >> 6, lane = tid & 63;
    int wm = wave >> 1, wn = wave & 1;
    int quad = lane >> 4, l16 = lane & 15;
    size_t bhbase = (size_t)(b * NHEADS + h) * LN_TOK + t0;
    if (tid < 128) { g[tid] = gcum[bhbase + tid]; dts[tid] = dtp[bhbase + tid]; }
    floatx4 acc[4][4] = {};
    size_t abase = bhbase * GNN;                       // Bh rows [s][n]
    size_t bbase = (size_t)(b * LN_TOK + t0) * GNN;    // Csh rows [t][n]
    for (int k0 = 0; k0 < 128; k0 += 64) {
#pragma unroll
        for (int p = 0; p < 4; p++) {
            int i = p * 256 + tid;
            int row = i >> 3, kk = (i & 7) << 3;
            *(int4*)&As[row * GPAD + kk] = *(const int4*)&Bh[abase + (size_t)row * GNN + k0 + kk];
            *(int4*)&Bs[row * GPAD + kk] = *(const int4*)&Csh[bbase + (size_t)row * GNN + k0 + kk];
        }
        __syncthreads();
#pragma unroll
        for (int ks = 0; ks < 64; ks += 32) {
            shortx8 af[4], bfr[4];
#pragma unroll
            for (int i = 0; i < 4; i++)
                af[i] = *(shortx8*)&As[(wm * 64 + i * 16 + l16) * GPAD + ks + (quad << 3)];
#pragma unroll
            for (int j = 0; j < 4; j++)
                bfr[j] = *(shortx8*)&Bs[(wn * 64 + j * 16 + l16) * GPAD + ks + (quad << 3)];
#pragma unroll
            for (int i = 0; i < 4; i++)
#pragma unroll
                for (int j = 0; j < 4; j++)
                    acc[i][j] = __builtin_amdgcn_mfma_f32_16x16x32_bf16(af[i], bfr[j], acc[i][j], 0, 0, 0);
        }
        __syncthreads();
    }
    size_t mb = (size_t)blk * (CHUNK * CHUNK);
#pragma unroll
    for (int i = 0; i < 4; i++) {
        int s0 = wm * 64 + i * 16 + quad * 4;
#pragma unroll
        for (int j = 0; j < 4; j++) {
            int t = wn * 64 + j * 16 + l16;
            u16 o[4];
#pragma unroll
            for (int r = 0; r < 4; r++) {
                int s = s0 + r;
                float v = (s <= t) ? acc[i][j][r] * __expf(g[t] - g[s]) * dts[s] : 0.f;
                o[r] = f2b(v);
            }
            u32 lo = (u32)o[0] | ((u32)o[1] << 16);
            u32 hi = (u32)o[2] | ((u32)o[3] << 16);
            *(uint2*)&Mb[mb + (size_t)t * CHUNK + s0] = make_uint2(lo, hi);
        }
    }
}

// ---------------- chunkS (fp32 vector): states[p][n] = sum_s x[s][p]*Bh'[s][n]
__global__ void k_chunkS(const u16* __restrict__ Bh, const u16* __restrict__ xsh,
                         const float* __restrict__ gcum, const float* __restrict__ dtp,
                         float* __restrict__ states) {
    int blk = blockIdx.x;
    int c = blk & 31, h = (blk >> 5) & 7, b = blk >> 8;
    int t0 = c * CHUNK;
    int tid = threadIdx.x;
    int tr = tid >> 4, tc = tid & 15;
    __shared__ float Bt[16][129];
    __shared__ float Xt[16][129];
    __shared__ float esc[128];
    size_t bhbase = (size_t)(b * NHEADS + h) * LN_TOK + t0;
    if (tid < 128) {
        float gl = gcum[bhbase + 127];
        esc[tid] = __expf(gl - gcum[bhbase + tid]) * dtp[bhbase + tid];
    }
    __syncthreads();
    float acc[8][8];
#pragma unroll
    for (int i = 0; i < 8; i++)
#pragma unroll
        for (int j = 0; j < 8; j++) acc[i][j] = 0.f;
    size_t xrow = (size_t)(b * LN_TOK + t0) * GNN;
    size_t brow = bhbase * GNN;
    for (int s0 = 0; s0 < 128; s0 += 16) {
        for (int i = tid; i < 16 * 128; i += 256) {
            int ss = i >> 7, n = i & 127;
            Bt[ss][n] = b2f(Bh[brow + (size_t)(s0 + ss) * GNN + n]) * esc[s0 + ss];
            Xt[ss][n] = b2f(xsh[xrow + (size_t)(s0 + ss) * GNN + n]);
        }
        __syncthreads();
#pragma unroll
        for (int kk = 0; kk < 16; kk++) {
            float a[8], bb[8];
#pragma unroll
            for (int i = 0; i < 8; i++) a[i] = Xt[kk][tr * 8 + i];
#pragma unroll
            for (int j = 0; j < 8; j++) bb[j] = Bt[kk][tc * 8 + j];
#pragma unroll
            for (int i = 0; i < 8; i++)
#pragma unroll
                for (int j = 0; j < 8; j++) acc[i][j] += a[i] * bb[j];
        }
        __syncthreads();
    }
    size_t sbase = (size_t)blk * 16384;
#pragma unroll
    for (int i = 0; i < 8; i++)
#pragma unroll
        for (int j = 0; j < 8; j++)
            states[sbase + (size_t)(tr * 8 + i) * CHUNK + tc * 8 + j] = acc[i][j];
}

// ---------------- inter-chunk scan (in-place) --------------------------------
__global__ void k_scan(float* __restrict__ states, const float* __restrict__ gcum) {
    int idx = blockIdx.x * 256 + threadIdx.x;
    int bh = idx >> 14;
    int np = idx & 16383;
    float run = 0.f;
    size_t base = (size_t)bh * NCHUNK * 16384 + np;
    size_t gb = (size_t)bh * LN_TOK;
    for (int c = 0; c < NCHUNK; c++) {
        float G = __expf(gcum[gb + c * CHUNK + 127]);
        float l = states[base + (size_t)c * 16384];
        states[base + (size_t)c * 16384] = run;
        run = G * run + l;
    }
}

// ---------------- chunkY (MFMA): y = eg[t]*C @ S0^T + Mb @ X^T ---------------
__global__ __launch_bounds__(256) void k_chunkY(const u16* __restrict__ Csh,
                                                const float* __restrict__ states,
                                                const u16* __restrict__ Mb,
                                                const u16* __restrict__ XT,
                                                const float* __restrict__ gcum,
                                                float* __restrict__ y) {
    int blk = blockIdx.x;
    int c = blk & 31, h = (blk >> 5) & 7, b = blk >> 8;
    int t0 = c * CHUNK;
    __shared__ u16 As[128 * GPAD];
    __shared__ u16 Bs[128 * GPAD];
    __shared__ float eg[128];
    int tid = threadIdx.x;
    int wave = tid >> 6, lane = tid & 63;
    int wm = wave >> 1, wn = wave & 1;
    int quad = lane >> 4, l16 = lane & 15;
    size_t bhbase = (size_t)(b * NHEADS + h) * LN_TOK + t0;
    if (tid < 128) eg[tid] = __expf(gcum[bhbase + tid]);
    __syncthreads();
    floatx4 acc[4][4] = {};
    size_t crow = (size_t)(b * LN_TOK + t0) * GNN;
    size_t sbase = (size_t)blk * 16384;
    size_t mbase = (size_t)blk * 16384;
    size_t xtb = (size_t)(b * GNN) * LN_TOK + t0;
    // phase 1: K = n (eg[t]*Csh, states[p][n])
    for (int k0 = 0; k0 < 128; k0 += 64) {
#pragma unroll
        for (int p = 0; p < 4; p++) {
            int i = p * 256 + tid;
            int row = i >> 3, kk = (i & 7) << 3;
            int4 raw = *(const int4*)&Csh[crow + (size_t)row * GNN + k0 + kk];
            float e = eg[row];
            u16* rp = (u16*)&raw;
            u32 w[4];
#pragma unroll
            for (int q = 0; q < 4; q++) {
                u16 a = f2b(b2f(rp[2 * q]) * e);
                u16 bb = f2b(b2f(rp[2 * q + 1]) * e);
                w[q] = (u32)a | ((u32)bb << 16);
            }
            *(int4*)&As[row * GPAD + kk] = make_int4(w[0], w[1], w[2], w[3]);
            float4 v0 = *(const float4*)&states[sbase + (size_t)row * CHUNK + k0 + kk];
            float4 v1 = *(const float4*)&states[sbase + (size_t)row * CHUNK + k0 + kk + 4];
            u32 x0 = (u32)f2b(v0.x) | ((u32)f2b(v0.y) << 16);
            u32 x1 = (u32)f2b(v0.z) | ((u32)f2b(v0.w) << 16);
            u32 x2 = (u32)f2b(v1.x) | ((u32)f2b(v1.y) << 16);
            u32 x3 = (u32)f2b(v1.z) | ((u32)f2b(v1.w) << 16);
            *(int4*)&Bs[row * GPAD + kk] = make_int4(x0, x1, x2, x3);
        }
        __syncthreads();
#pragma unroll
        for (int ks = 0; ks < 64; ks += 32) {
            shortx8 af[4], bfr[4];
#pragma unroll
            for (int i = 0; i < 4; i++)
                af[i] = *(shortx8*)&As[(wm * 64 + i * 16 + l16) * GPAD + ks + (quad << 3)];
#pragma unroll
            for (int j = 0; j < 4; j++)
                bfr[j] = *(shortx8*)&Bs[(wn * 64 + j * 16 + l16) * GPAD + ks + (quad << 3)];
#pragma unroll
            for (int i = 0; i < 4; i++)
#pragma unroll
                for (int j = 0; j < 4; j++)
                    acc[i][j] = __builtin_amdgcn_mfma_f32_16x16x32_bf16(af[i], bfr[j], acc[i][j], 0, 0, 0);
        }
        __syncthreads();
    }
    // phase 2: K = s (Mb[t][s], XT[p][s])
    for (int k0 = 0; k0 < 128; k0 += 64) {
#pragma unroll
        for (int p = 0; p < 4; p++) {
            int i = p * 256 + tid;
            int row = i >> 3, kk = (i & 7) << 3;
            *(int4*)&As[row * GPAD + kk] = *(const int4*)&Mb[mbase + (size_t)row * CHUNK + k0 + kk];
            *(int4*)&Bs[row * GPAD + kk] = *(const int4*)&XT[xtb + (size_t)row * LN_TOK + k0 + kk];
        }
        __syncthreads();
#pragma unroll
        for (int ks = 0; ks < 64; ks += 32) {
            shortx8 af[4], bfr[4];
#pragma unroll
            for (int i = 0; i < 4; i++)
                af[i] = *(shortx8*)&As[(wm * 64 + i * 16 + l16) * GPAD + ks + (quad << 3)];
#pragma unroll
            for (int j = 0; j < 4; j++)
                bfr[j] = *(shortx8*)&Bs[(wn * 64 + j * 16 + l16) * GPAD + ks + (quad << 3)];
#pragma unroll
            for (int i = 0; i < 4; i++)
#pragma unroll
                for (int j = 0; j < 4; j++)
                    acc[i][j] = __builtin_amdgcn_mfma_f32_16x16x32_bf16(af[i], bfr[j], acc[i][j], 0, 0, 0);
        }
        __syncthreads();
    }
#pragma unroll
    for (int i = 0; i < 4; i++) {
        int t = wm * 64 + i * 16 + quad * 4;
#pragma unroll
        for (int j = 0; j < 4; j++) {
            int p = wn * 64 + j * 16 + l16;
#pragma unroll
            for (int r = 0; r < 4; r++)
                y[((size_t)(b * LN_TOK + t0 + t + r)) * DINNER + h * GNN + p] = acc[i][j][r];
        }
    }
}

// ---------------- gating + D*x + RMSNorm -> bf16 ybuf ------------------------
__global__ void k_gate(const float* __restrict__ y, const float* __restrict__ zx,
                       const u16* __restrict__ xsh, const float* __restrict__ Dp,
                       const float* __restrict__ rw, u16* __restrict__ ybuf) {
    int row = blockIdx.x;
    int tid = threadIdx.x;
    size_t yb = (size_t)row * DINNER;
    size_t zb = (size_t)row * ZSTRIDE;
    size_t xb = (size_t)row * GNN;
    float yg[4];
    float ss = 0.f;
#pragma unroll
    for (int q = 0; q < 4; q++) {
        int k = tid * 4 + q;
        int h = k >> 7, p = k & 127;
        float z = zx[zb + k];
        float v = (y[yb + k] + Dp[h] * b2f(xsh[xb + p])) * z * sigmoidf_(z);
        yg[q] = v;
        ss += v * v;
    }
    __shared__ float red[256];
    red[tid] = ss;
    __syncthreads();
    for (int off = 128; off > 0; off >>= 1) {
        if (tid < off) red[tid] += red[tid + off];
        __syncthreads();
    }
    float scale = rsqrtf(red[0] * (1.f / DINNER) + EPSF);
#pragma unroll
    for (int q = 0; q < 4; q++) {
        int k = tid * 4 + q;
        ybuf[yb + k] = f2b(yg[q] * scale * rw[k]);
    }
}

extern "C" void kernel_launch(void* const* d_in, const int* in_sizes, int n_in,
                              void* d_out, int out_size, void* d_ws, size_t ws_size,
                              hipStream_t stream) {
    (void)in_sizes; (void)n_in; (void)out_size; (void)ws_size;
    const float* u        = (const float*)d_in[0];
    const float* ln_gamma = (const float*)d_in[1];
    const float* ln_beta  = (const float*)d_in[2];
    const float* W_in     = (const float*)d_in[3];
    const float* conv_w   = (const float*)d_in[4];
    const float* conv_b   = (const float*)d_in[5];
    const float* dt_bias  = (const float*)d_in[6];
    const float* A_log    = (const float*)d_in[7];
    const float* D_param  = (const float*)d_in[8];
    const float* B_scale  = (const float*)d_in[9];
    const float* rms_w    = (const float*)d_in[10];
    const float* W_out    = (const float*)d_in[11];
    float* out = (float*)d_out;

    char* ws = (char*)d_ws;
    u16*   xn_b   = (u16*)ws;                 ws += (size_t)NROWS * DMODEL * 2;        // 4 MB
    u16*   Wt     = (u16*)ws;                 ws += (size_t)ZSTRIDE * DMODEL * 2;      // 1.25 MB
    u16*   Wot    = (u16*)ws;                 ws += (size_t)DMODEL * DINNER * 2;       // 0.5 MB
    float* zx     = (float*)ws;               ws += (size_t)NROWS * ZSTRIDE * 4;       // 79.7 MB
    u16*   xsh    = (u16*)ws;                 ws += (size_t)NROWS * GNN * 2;           // 2 MB
    u16*   Bsh    = (u16*)ws;                 ws += (size_t)NROWS * GNN * 2;           // 2 MB
    u16*   Csh    = (u16*)ws;                 ws += (size_t)NROWS * GNN * 2;           // 2 MB
    u16*   Bh     = (u16*)ws;                 ws += (size_t)NB * NHEADS * LN_TOK * GNN * 2; // 16.8 MB
    u16*   XT     = (u16*)ws;                 ws += (size_t)NB * GNN * LN_TOK * 2;     // 2 MB
    float* dtp    = (float*)ws;               ws += (size_t)NB * NHEADS * LN_TOK * 4;
    float* laa    = (float*)ws;               ws += (size_t)NB * NHEADS * LN_TOK * 4;
    float* gcum   = (float*)ws;               ws += (size_t)NB * NHEADS * LN_TOK * 4;
    u16*   Mb     = (u16*)ws;                 ws += (size_t)512 * 16384 * 2;           // 16.8 MB
    float* states = (float*)ws;               ws += (size_t)512 * 16384 * 4;           // 33.6 MB
    float* ybig   = (float*)ws;               ws += (size_t)NROWS * DINNER * 4;        // 33.6 MB
    u16*   ybuf   = Mb;  // reuse (Mb dead after k_chunkY)

    k_ln<<<NROWS, 256, 0, stream>>>(u, ln_gamma, ln_beta, xn_b);

    k_tcast<<<dim3(ZSTRIDE / 64, DMODEL / 64), 256, 0, stream>>>(W_in, Wt, DMODEL, DPROJ, ZSTRIDE);
    k_tcast<<<dim3(DMODEL / 64, DINNER / 64), 256, 0, stream>>>(W_out, Wot, DINNER, DMODEL, DMODEL);

    k_gemm<<<dim3(ZSTRIDE / 128, NROWS / 128), 256, 0, stream>>>(xn_b, Wt, zx, DMODEL, ZSTRIDE, nullptr);

    k_conv<<<NROWS, 256, 0, stream>>>(zx, conv_w, conv_b, dt_bias, A_log, xsh, Bsh, Csh, dtp, laa);

    k_bh<<<NROWS, 128, 0, stream>>>(Bsh, B_scale, Bh);

    k_tbf<<<dim3(GNN / 64, LN_TOK / 64, NB), 256, 0, stream>>>(xsh, XT);

    k_prefix<<<NB * NHEADS * NCHUNK, 128, 0, stream>>>(laa, gcum);

    k_chunkM<<<NB * NHEADS * NCHUNK, 256, 0, stream>>>(Bh, Csh, gcum, dtp, Mb);

    k_chunkS<<<NB * NHEADS * NCHUNK, 256, 0, stream>>>(Bh, xsh, gcum, dtp, states);

    k_scan<<<(NB * NHEADS * 16384) / 256, 256, 0, stream>>>(states, gcum);

    k_chunkY<<<NB * NHEADS * NCHUNK, 256, 0, stream>>>(Csh, states, Mb, XT, gcum, ybig);

    k_gate<<<NROWS, 256, 0, stream>>>(ybig, zx, xsh, D_param, rms_w, ybuf);

    k_gemm<<<dim3(DMODEL / 128, NROWS / 128), 256, 0, stream>>>(ybuf, Wot, out, DINNER, DMODEL, u);
}

// Round 3
// 266.988 us; speedup vs baseline: 3.9253x; 1.2498x over previous
//
#include <hip/hip_runtime.h>
#include <math.h>

#define LN_TOK 4096
#define NB 2
#define NROWS (NB * LN_TOK)          // 8192
#define DMODEL 256
#define DINNER 1024
#define NHEADS 8
#define GNN 128
#define DPROJ 2312
#define ZSTRIDE 2432                 // padded in-proj N (19*128)
#define EPSF 1e-5f
#define NCHUNK 32
#define CHUNK 128
#define GPAD 72                      // LDS row stride in bf16 elems (144 B)

typedef unsigned short u16;
typedef unsigned int u32;
typedef __attribute__((ext_vector_type(8))) short shortx8;
typedef __attribute__((ext_vector_type(4))) float floatx4;

__device__ __forceinline__ float sigmoidf_(float v) { return 1.f / (1.f + __expf(-v)); }
__device__ __forceinline__ float siluf_(float v)    { return v / (1.f + __expf(-v)); }
__device__ __forceinline__ float softplusf_(float v){ return v > 20.f ? v : log1pf(__expf(v)); }
__device__ __forceinline__ float b2f(u16 h) { return __uint_as_float(((u32)h) << 16); }
__device__ __forceinline__ u16 f2b(float f) {
    u32 u = __float_as_uint(f);
    u32 r = (u + 0x7fffu + ((u >> 16) & 1u)) >> 16;
    return (u16)r;
}

// ---------------- LayerNorm -> bf16 xn ----------------
__global__ void k_ln(const float* __restrict__ u, const float* __restrict__ gam,
                     const float* __restrict__ bet, u16* __restrict__ xn) {
    int row = blockIdx.x;
    int tid = threadIdx.x;
    float v = u[(size_t)row * DMODEL + tid];
    __shared__ float s1[256], s2[256];
    s1[tid] = v; s2[tid] = v * v;
    __syncthreads();
    for (int off = 128; off > 0; off >>= 1) {
        if (tid < off) { s1[tid] += s1[tid + off]; s2[tid] += s2[tid + off]; }
        __syncthreads();
    }
    float mean = s1[0] * (1.f / DMODEL);
    float var  = s2[0] * (1.f / DMODEL) - mean * mean;
    float r = rsqrtf(var + EPSF);
    xn[(size_t)row * DMODEL + tid] = f2b((v - mean) * r * gam[tid] + bet[tid]);
}

// ---------------- transpose-cast fp32 [R][C] -> bf16 [Cp][R], zero pad rows --
__global__ void k_tcast(const float* __restrict__ in, u16* __restrict__ out,
                        int R, int C, int Cp) {
    __shared__ float tile[64][65];
    int c0 = blockIdx.x * 64, r0 = blockIdx.y * 64;
    int tx = threadIdx.x & 63, ty = threadIdx.x >> 6;
    for (int rr = ty; rr < 64; rr += 4) {
        int r = r0 + rr, c = c0 + tx;
        tile[rr][tx] = (r < R && c < C) ? in[(size_t)r * C + c] : 0.f;
    }
    __syncthreads();
    for (int cc = ty; cc < 64; cc += 4) {
        int c = c0 + cc, r = r0 + tx;
        if (c < Cp && r < R) out[(size_t)c * R + r] = f2b(tile[tx][cc]);
    }
}

// ---------------- bf16 transpose: in [b*4096+t][128] -> out [b*128+p][4096] --
__global__ void k_tbf(const u16* __restrict__ in, u16* __restrict__ out) {
    __shared__ u16 tile[64][65];
    int b = blockIdx.z;
    int p0 = blockIdx.x * 64, t0 = blockIdx.y * 64;
    int tx = threadIdx.x & 63, ty = threadIdx.x >> 6;
    for (int tt = ty; tt < 64; tt += 4)
        tile[tt][tx] = in[((size_t)(b * LN_TOK + t0 + tt)) * GNN + p0 + tx];
    __syncthreads();
    for (int pp = ty; pp < 64; pp += 4)
        out[((size_t)(b * GNN + p0 + pp)) * LN_TOK + t0 + tx] = tile[tx][pp];
}

// ---------------- bf16 MFMA GEMM: C = A(MxK) @ Bt(NxK)^T [+addC], 128x128 ---
__global__ __launch_bounds__(256) void k_gemm(const u16* __restrict__ A,
                                              const u16* __restrict__ Bt,
                                              float* __restrict__ C,
                                              int K, int ldc,
                                              const float* __restrict__ addC) {
    __shared__ u16 As[128 * GPAD];
    __shared__ u16 Bs[128 * GPAD];
    int tid = threadIdx.x;
    int wave = tid >> 6, lane = tid & 63;
    int wm = wave >> 1, wn = wave & 1;
    int quad = lane >> 4, l16 = lane & 15;
    int m0 = blockIdx.y * 128, n0 = blockIdx.x * 128;
    floatx4 acc[4][4] = {};
    for (int k0 = 0; k0 < K; k0 += 64) {
#pragma unroll
        for (int p = 0; p < 4; p++) {
            int i = p * 256 + tid;
            int row = i >> 3, kk = (i & 7) << 3;
            *(int4*)&As[row * GPAD + kk] = *(const int4*)&A[(size_t)(m0 + row) * K + k0 + kk];
            *(int4*)&Bs[row * GPAD + kk] = *(const int4*)&Bt[(size_t)(n0 + row) * K + k0 + kk];
        }
        __syncthreads();
#pragma unroll
        for (int ks = 0; ks < 64; ks += 32) {
            shortx8 af[4], bfr[4];
#pragma unroll
            for (int i = 0; i < 4; i++)
                af[i] = *(shortx8*)&As[(wm * 64 + i * 16 + l16) * GPAD + ks + (quad << 3)];
#pragma unroll
            for (int j = 0; j < 4; j++)
                bfr[j] = *(shortx8*)&Bs[(wn * 64 + j * 16 + l16) * GPAD + ks + (quad << 3)];
#pragma unroll
            for (int i = 0; i < 4; i++)
#pragma unroll
                for (int j = 0; j < 4; j++)
                    acc[i][j] = __builtin_amdgcn_mfma_f32_16x16x32_bf16(af[i], bfr[j], acc[i][j], 0, 0, 0);
        }
        __syncthreads();
    }
#pragma unroll
    for (int i = 0; i < 4; i++) {
        int row = m0 + wm * 64 + i * 16 + quad * 4;
#pragma unroll
        for (int j = 0; j < 4; j++) {
            int col = n0 + wn * 64 + j * 16 + l16;
#pragma unroll
            for (int r = 0; r < 4; r++) {
                size_t idx = (size_t)(row + r) * ldc + col;
                float v = acc[i][j][r];
                if (addC) v += addC[idx];
                C[idx] = v;
            }
        }
    }
}

// ---------------- bf16 MFMA GEMM variant: 128x64 tile (out-proj) -------------
__global__ __launch_bounds__(256) void k_gemm2(const u16* __restrict__ A,
                                               const u16* __restrict__ Bt,
                                               float* __restrict__ C,
                                               int K, int ldc,
                                               const float* __restrict__ addC) {
    __shared__ u16 As[128 * GPAD];
    __shared__ u16 Bs[64 * GPAD];
    int tid = threadIdx.x;
    int wave = tid >> 6, lane = tid & 63;
    int wm = wave >> 1, wn = wave & 1;
    int quad = lane >> 4, l16 = lane & 15;
    int m0 = blockIdx.y * 128, n0 = blockIdx.x * 64;
    floatx4 acc[4][2] = {};
    for (int k0 = 0; k0 < K; k0 += 64) {
#pragma unroll
        for (int p = 0; p < 4; p++) {
            int i = p * 256 + tid;
            int row = i >> 3, kk = (i & 7) << 3;
            *(int4*)&As[row * GPAD + kk] = *(const int4*)&A[(size_t)(m0 + row) * K + k0 + kk];
        }
#pragma unroll
        for (int p = 0; p < 2; p++) {
            int i = p * 256 + tid;
            int row = i >> 3, kk = (i & 7) << 3;
            *(int4*)&Bs[row * GPAD + kk] = *(const int4*)&Bt[(size_t)(n0 + row) * K + k0 + kk];
        }
        __syncthreads();
#pragma unroll
        for (int ks = 0; ks < 64; ks += 32) {
            shortx8 af[4], bfr[2];
#pragma unroll
            for (int i = 0; i < 4; i++)
                af[i] = *(shortx8*)&As[(wm * 64 + i * 16 + l16) * GPAD + ks + (quad << 3)];
#pragma unroll
            for (int j = 0; j < 2; j++)
                bfr[j] = *(shortx8*)&Bs[(wn * 32 + j * 16 + l16) * GPAD + ks + (quad << 3)];
#pragma unroll
            for (int i = 0; i < 4; i++)
#pragma unroll
                for (int j = 0; j < 2; j++)
                    acc[i][j] = __builtin_amdgcn_mfma_f32_16x16x32_bf16(af[i], bfr[j], acc[i][j], 0, 0, 0);
        }
        __syncthreads();
    }
#pragma unroll
    for (int i = 0; i < 4; i++) {
        int row = m0 + wm * 64 + i * 16 + quad * 4;
#pragma unroll
        for (int j = 0; j < 2; j++) {
            int col = n0 + wn * 32 + j * 16 + l16;
#pragma unroll
            for (int r = 0; r < 4; r++) {
                size_t idx = (size_t)(row + r) * ldc + col;
                float v = acc[i][j][r];
                if (addC) v += addC[idx];
                C[idx] = v;
            }
        }
    }
}

// ---------------- conv(K=4, causal) + SiLU + splits + dt/A prep --------------
__global__ void k_conv(const float* __restrict__ zx, const float* __restrict__ cw,
                       const float* __restrict__ cb, const float* __restrict__ dt_bias,
                       const float* __restrict__ A_log,
                       u16* __restrict__ xsh, u16* __restrict__ Bsh,
                       u16* __restrict__ Csh, float* __restrict__ dtp,
                       float* __restrict__ laa) {
    int bt = blockIdx.x;
    int b = bt / LN_TOK, t = bt % LN_TOK;
    int tid = threadIdx.x;
    __shared__ float sv[1280];
#pragma unroll
    for (int i = 0; i < 5; i++) {
        int c = tid + i * 256;
        float acc = cb[c];
#pragma unroll
        for (int k = 0; k < 4; k++) {
            int tt = t + k - 3;
            if (tt >= 0)
                acc += zx[((size_t)(b * LN_TOK + tt)) * ZSTRIDE + DINNER + c] * cw[c * 4 + k];
        }
        sv[c] = siluf_(acc);
    }
    __syncthreads();
    size_t rowp = (size_t)(b * LN_TOK + t) * GNN;
    if (tid < 128) {
        float s = 0.f;
#pragma unroll
        for (int h = 0; h < NHEADS; h++) s += sv[h * 128 + tid];
        xsh[rowp + tid] = f2b(s * 0.125f);
    } else {
        int n = tid - 128;
        Bsh[rowp + n] = f2b(sv[1024 + n]);
        Csh[rowp + n] = f2b(sv[1152 + n]);
    }
    if (tid < NHEADS) {
        int h = tid;
        float dtv = zx[(size_t)(b * LN_TOK + t) * ZSTRIDE + 2304 + h] + dt_bias[h];
        float dp = softplusf_(dtv);
        size_t idx = ((size_t)(b * NHEADS + h)) * LN_TOK + t;
        dtp[idx] = dp;
        laa[idx] = -__expf(A_log[h]) * dp;
    }
}

// ---------------- per-chunk inclusive prefix sum of log-decay ----------------
__global__ void k_prefix(const float* __restrict__ laa, float* __restrict__ gcum) {
    int blk = blockIdx.x;
    int bh = blk / NCHUNK, c = blk % NCHUNK;
    int tid = threadIdx.x;
    __shared__ float s[128];
    size_t base = (size_t)bh * LN_TOK + c * CHUNK;
    s[tid] = laa[base + tid];
    __syncthreads();
    for (int off = 1; off < 128; off <<= 1) {
        float v = (tid >= off) ? s[tid - off] : 0.f;
        __syncthreads();
        s[tid] += v;
        __syncthreads();
    }
    gcum[base + tid] = s[tid];
}

// ---------------- chunkM (MFMA): Mb[t][s] = mask*exp(g_t-g_s)*dt_s*(B'_s.C_t)
__global__ __launch_bounds__(256) void k_chunkM(const u16* __restrict__ Bsh,
                                                const u16* __restrict__ Csh,
                                                const float* __restrict__ scale,
                                                const float* __restrict__ gcum,
                                                const float* __restrict__ dtp,
                                                u16* __restrict__ Mb) {
    int blk = blockIdx.x;
    int c = blk & 31, h = (blk >> 5) & 7, b = blk >> 8;
    int t0 = c * CHUNK;
    __shared__ u16 As[128 * GPAD];
    __shared__ u16 Bs[128 * GPAD];
    __shared__ float g[128], dts[128], sc[128];
    int tid = threadIdx.x;
    int wave = tid >> 6, lane = tid & 63;
    int wm = wave >> 1, wn = wave & 1;
    int quad = lane >> 4, l16 = lane & 15;
    size_t bhbase = (size_t)(b * NHEADS + h) * LN_TOK + t0;
    if (tid < 128) {
        g[tid] = gcum[bhbase + tid];
        dts[tid] = dtp[bhbase + tid];
        sc[tid] = scale[h * GNN + tid];
    }
    __syncthreads();
    floatx4 acc[4][4] = {};
    size_t rbase = (size_t)(b * LN_TOK + t0) * GNN;   // token rows
    for (int k0 = 0; k0 < 128; k0 += 64) {
#pragma unroll
        for (int p = 0; p < 4; p++) {
            int i = p * 256 + tid;
            int row = i >> 3, kk = (i & 7) << 3;
            int4 raw = *(const int4*)&Bsh[rbase + (size_t)row * GNN + k0 + kk];
            u16* rp = (u16*)&raw;
            u32 w[4];
#pragma unroll
            for (int q = 0; q < 4; q++) {
                u16 a  = f2b(b2f(rp[2 * q])     * sc[k0 + kk + 2 * q]);
                u16 bb = f2b(b2f(rp[2 * q + 1]) * sc[k0 + kk + 2 * q + 1]);
                w[q] = (u32)a | ((u32)bb << 16);
            }
            *(int4*)&As[row * GPAD + kk] = make_int4(w[0], w[1], w[2], w[3]);
            *(int4*)&Bs[row * GPAD + kk] = *(const int4*)&Csh[rbase + (size_t)row * GNN + k0 + kk];
        }
        __syncthreads();
#pragma unroll
        for (int ks = 0; ks < 64; ks += 32) {
            shortx8 af[4], bfr[4];
#pragma unroll
            for (int i = 0; i < 4; i++)
                af[i] = *(shortx8*)&As[(wm * 64 + i * 16 + l16) * GPAD + ks + (quad << 3)];
#pragma unroll
            for (int j = 0; j < 4; j++)
                bfr[j] = *(shortx8*)&Bs[(wn * 64 + j * 16 + l16) * GPAD + ks + (quad << 3)];
#pragma unroll
            for (int i = 0; i < 4; i++)
#pragma unroll
                for (int j = 0; j < 4; j++)
                    acc[i][j] = __builtin_amdgcn_mfma_f32_16x16x32_bf16(af[i], bfr[j], acc[i][j], 0, 0, 0);
        }
        __syncthreads();
    }
    size_t mb = (size_t)blk * (CHUNK * CHUNK);
#pragma unroll
    for (int i = 0; i < 4; i++) {
        int s0 = wm * 64 + i * 16 + quad * 4;
#pragma unroll
        for (int j = 0; j < 4; j++) {
            int t = wn * 64 + j * 16 + l16;
            u16 o[4];
#pragma unroll
            for (int r = 0; r < 4; r++) {
                int s = s0 + r;
                float v = (s <= t) ? acc[i][j][r] * __expf(g[t] - g[s]) * dts[s] : 0.f;
                o[r] = f2b(v);
            }
            u32 lo = (u32)o[0] | ((u32)o[1] << 16);
            u32 hi = (u32)o[2] | ((u32)o[3] << 16);
            *(uint2*)&Mb[mb + (size_t)t * CHUNK + s0] = make_uint2(lo, hi);
        }
    }
}

// ---------------- chunkS (MFMA): states[p][n] = sum_s XT[p][s]*BT[n][s]*sc*esc
// computed as C[m=n][col=p]; output bf16
__global__ __launch_bounds__(256) void k_chunkS(const u16* __restrict__ BT,
                                                const u16* __restrict__ XT,
                                                const float* __restrict__ scale,
                                                const float* __restrict__ gcum,
                                                const float* __restrict__ dtp,
                                                u16* __restrict__ states) {
    int blk = blockIdx.x;
    int c = blk & 31, h = (blk >> 5) & 7, b = blk >> 8;
    int t0 = c * CHUNK;
    __shared__ u16 As[128 * GPAD];
    __shared__ u16 Bs[128 * GPAD];
    __shared__ float esc[128], scl[128];
    int tid = threadIdx.x;
    int wave = tid >> 6, lane = tid & 63;
    int wm = wave >> 1, wn = wave & 1;
    int quad = lane >> 4, l16 = lane & 15;
    size_t bhbase = (size_t)(b * NHEADS + h) * LN_TOK + t0;
    if (tid < 128) {
        float gl = gcum[bhbase + 127];
        esc[tid] = __expf(gl - gcum[bhbase + tid]) * dtp[bhbase + tid];
        scl[tid] = scale[h * GNN + tid];
    }
    __syncthreads();
    floatx4 acc[4][4] = {};
    size_t tbase = (size_t)(b * GNN) * LN_TOK + t0;   // rows of BT / XT
    for (int k0 = 0; k0 < 128; k0 += 64) {
#pragma unroll
        for (int p = 0; p < 4; p++) {
            int i = p * 256 + tid;
            int row = i >> 3, kk = (i & 7) << 3;
            int4 raw = *(const int4*)&BT[tbase + (size_t)row * LN_TOK + k0 + kk];
            u16* rp = (u16*)&raw;
            float sr = scl[row];
            u32 w[4];
#pragma unroll
            for (int q = 0; q < 4; q++) {
                u16 a  = f2b(b2f(rp[2 * q])     * sr * esc[k0 + kk + 2 * q]);
                u16 bb = f2b(b2f(rp[2 * q + 1]) * sr * esc[k0 + kk + 2 * q + 1]);
                w[q] = (u32)a | ((u32)bb << 16);
            }
            *(int4*)&As[row * GPAD + kk] = make_int4(w[0], w[1], w[2], w[3]);
            *(int4*)&Bs[row * GPAD + kk] = *(const int4*)&XT[tbase + (size_t)row * LN_TOK + k0 + kk];
        }
        __syncthreads();
#pragma unroll
        for (int ks = 0; ks < 64; ks += 32) {
            shortx8 af[4], bfr[4];
#pragma unroll
            for (int i = 0; i < 4; i++)
                af[i] = *(shortx8*)&As[(wm * 64 + i * 16 + l16) * GPAD + ks + (quad << 3)];
#pragma unroll
            for (int j = 0; j < 4; j++)
                bfr[j] = *(shortx8*)&Bs[(wn * 64 + j * 16 + l16) * GPAD + ks + (quad << 3)];
#pragma unroll
            for (int i = 0; i < 4; i++)
#pragma unroll
                for (int j = 0; j < 4; j++)
                    acc[i][j] = __builtin_amdgcn_mfma_f32_16x16x32_bf16(af[i], bfr[j], acc[i][j], 0, 0, 0);
        }
        __syncthreads();
    }
    size_t sbase = (size_t)blk * 16384;
#pragma unroll
    for (int i = 0; i < 4; i++) {
        int n0 = wm * 64 + i * 16 + quad * 4;
#pragma unroll
        for (int j = 0; j < 4; j++) {
            int p = wn * 64 + j * 16 + l16;
            u16 o[4];
#pragma unroll
            for (int r = 0; r < 4; r++) o[r] = f2b(acc[i][j][r]);
            u32 lo = (u32)o[0] | ((u32)o[1] << 16);
            u32 hi = (u32)o[2] | ((u32)o[3] << 16);
            *(uint2*)&states[sbase + (size_t)p * CHUNK + n0] = make_uint2(lo, hi);
        }
    }
}

// ---------------- inter-chunk scan (in-place, bf16 storage) ------------------
__global__ void k_scan(u16* __restrict__ states, const float* __restrict__ gcum) {
    int idx = blockIdx.x * 256 + threadIdx.x;
    int bh = idx >> 14;
    int np = idx & 16383;
    float run = 0.f;
    size_t base = (size_t)bh * NCHUNK * 16384 + np;
    size_t gb = (size_t)bh * LN_TOK;
    for (int c = 0; c < NCHUNK; c++) {
        float G = __expf(gcum[gb + c * CHUNK + 127]);
        float l = b2f(states[base + (size_t)c * 16384]);
        states[base + (size_t)c * 16384] = f2b(run);
        run = G * run + l;
    }
}

// ---------------- chunkY (MFMA): y = eg[t]*C @ S0^T + Mb @ X^T (bf16 out) ----
__global__ __launch_bounds__(256) void k_chunkY(const u16* __restrict__ Csh,
                                                const u16* __restrict__ states,
                                                const u16* __restrict__ Mb,
                                                const u16* __restrict__ XT,
                                                const float* __restrict__ gcum,
                                                u16* __restrict__ y) {
    int blk = blockIdx.x;
    int c = blk & 31, h = (blk >> 5) & 7, b = blk >> 8;
    int t0 = c * CHUNK;
    __shared__ u16 As[128 * GPAD];
    __shared__ u16 Bs[128 * GPAD];
    __shared__ float eg[128];
    int tid = threadIdx.x;
    int wave = tid >> 6, lane = tid & 63;
    int wm = wave >> 1, wn = wave & 1;
    int quad = lane >> 4, l16 = lane & 15;
    size_t bhbase = (size_t)(b * NHEADS + h) * LN_TOK + t0;
    if (tid < 128) eg[tid] = __expf(gcum[bhbase + tid]);
    __syncthreads();
    floatx4 acc[4][4] = {};
    size_t crow = (size_t)(b * LN_TOK + t0) * GNN;
    size_t sbase = (size_t)blk * 16384;
    size_t mbase = (size_t)blk * 16384;
    size_t xtb = (size_t)(b * GNN) * LN_TOK + t0;
    // phase 1: K = n (eg[t]*Csh, states[p][n] bf16)
    for (int k0 = 0; k0 < 128; k0 += 64) {
#pragma unroll
        for (int p = 0; p < 4; p++) {
            int i = p * 256 + tid;
            int row = i >> 3, kk = (i & 7) << 3;
            int4 raw = *(const int4*)&Csh[crow + (size_t)row * GNN + k0 + kk];
            float e = eg[row];
            u16* rp = (u16*)&raw;
            u32 w[4];
#pragma unroll
            for (int q = 0; q < 4; q++) {
                u16 a  = f2b(b2f(rp[2 * q]) * e);
                u16 bb = f2b(b2f(rp[2 * q + 1]) * e);
                w[q] = (u32)a | ((u32)bb << 16);
            }
            *(int4*)&As[row * GPAD + kk] = make_int4(w[0], w[1], w[2], w[3]);
            *(int4*)&Bs[row * GPAD + kk] = *(const int4*)&states[sbase + (size_t)row * CHUNK + k0 + kk];
        }
        __syncthreads();
#pragma unroll
        for (int ks = 0; ks < 64; ks += 32) {
            shortx8 af[4], bfr[4];
#pragma unroll
            for (int i = 0; i < 4; i++)
                af[i] = *(shortx8*)&As[(wm * 64 + i * 16 + l16) * GPAD + ks + (quad << 3)];
#pragma unroll
            for (int j = 0; j < 4; j++)
                bfr[j] = *(shortx8*)&Bs[(wn * 64 + j * 16 + l16) * GPAD + ks + (quad << 3)];
#pragma unroll
            for (int i = 0; i < 4; i++)
#pragma unroll
                for (int j = 0; j < 4; j++)
                    acc[i][j] = __builtin_amdgcn_mfma_f32_16x16x32_bf16(af[i], bfr[j], acc[i][j], 0, 0, 0);
        }
        __syncthreads();
    }
    // phase 2: K = s (Mb[t][s], XT[p][s])
    for (int k0 = 0; k0 < 128; k0 += 64) {
#pragma unroll
        for (int p = 0; p < 4; p++) {
            int i = p * 256 + tid;
            int row = i >> 3, kk = (i & 7) << 3;
            *(int4*)&As[row * GPAD + kk] = *(const int4*)&Mb[mbase + (size_t)row * CHUNK + k0 + kk];
            *(int4*)&Bs[row * GPAD + kk] = *(const int4*)&XT[xtb + (size_t)row * LN_TOK + k0 + kk];
        }
        __syncthreads();
#pragma unroll
        for (int ks = 0; ks < 64; ks += 32) {
            shortx8 af[4], bfr[4];
#pragma unroll
            for (int i = 0; i < 4; i++)
                af[i] = *(shortx8*)&As[(wm * 64 + i * 16 + l16) * GPAD + ks + (quad << 3)];
#pragma unroll
            for (int j = 0; j < 4; j++)
                bfr[j] = *(shortx8*)&Bs[(wn * 64 + j * 16 + l16) * GPAD + ks + (quad << 3)];
#pragma unroll
            for (int i = 0; i < 4; i++)
#pragma unroll
                for (int j = 0; j < 4; j++)
                    acc[i][j] = __builtin_amdgcn_mfma_f32_16x16x32_bf16(af[i], bfr[j], acc[i][j], 0, 0, 0);
        }
        __syncthreads();
    }
#pragma unroll
    for (int i = 0; i < 4; i++) {
        int t = wm * 64 + i * 16 + quad * 4;
#pragma unroll
        for (int j = 0; j < 4; j++) {
            int p = wn * 64 + j * 16 + l16;
#pragma unroll
            for (int r = 0; r < 4; r++)
                y[((size_t)(b * LN_TOK + t0 + t + r)) * DINNER + h * GNN + p] = f2b(acc[i][j][r]);
        }
    }
}

// ---------------- gating + D*x + RMSNorm -> bf16 ybuf ------------------------
__global__ void k_gate(const u16* __restrict__ y, const float* __restrict__ zx,
                       const u16* __restrict__ xsh, const float* __restrict__ Dp,
                       const float* __restrict__ rw, u16* __restrict__ ybuf) {
    int row = blockIdx.x;
    int tid = threadIdx.x;
    size_t yb = (size_t)row * DINNER;
    size_t zb = (size_t)row * ZSTRIDE;
    size_t xb = (size_t)row * GNN;
    float yg[4];
    float ss = 0.f;
#pragma unroll
    for (int q = 0; q < 4; q++) {
        int k = tid * 4 + q;
        int h = k >> 7, p = k & 127;
        float z = zx[zb + k];
        float v = (b2f(y[yb + k]) + Dp[h] * b2f(xsh[xb + p])) * z * sigmoidf_(z);
        yg[q] = v;
        ss += v * v;
    }
    __shared__ float red[256];
    red[tid] = ss;
    __syncthreads();
    for (int off = 128; off > 0; off >>= 1) {
        if (tid < off) red[tid] += red[tid + off];
        __syncthreads();
    }
    float scale = rsqrtf(red[0] * (1.f / DINNER) + EPSF);
#pragma unroll
    for (int q = 0; q < 4; q++) {
        int k = tid * 4 + q;
        ybuf[yb + k] = f2b(yg[q] * scale * rw[k]);
    }
}

extern "C" void kernel_launch(void* const* d_in, const int* in_sizes, int n_in,
                              void* d_out, int out_size, void* d_ws, size_t ws_size,
                              hipStream_t stream) {
    (void)in_sizes; (void)n_in; (void)out_size; (void)ws_size;
    const float* u        = (const float*)d_in[0];
    const float* ln_gamma = (const float*)d_in[1];
    const float* ln_beta  = (const float*)d_in[2];
    const float* W_in     = (const float*)d_in[3];
    const float* conv_w   = (const float*)d_in[4];
    const float* conv_b   = (const float*)d_in[5];
    const float* dt_bias  = (const float*)d_in[6];
    const float* A_log    = (const float*)d_in[7];
    const float* D_param  = (const float*)d_in[8];
    const float* B_scale  = (const float*)d_in[9];
    const float* rms_w    = (const float*)d_in[10];
    const float* W_out    = (const float*)d_in[11];
    float* out = (float*)d_out;

    char* ws = (char*)d_ws;
    u16*   xn_b   = (u16*)ws;                 ws += (size_t)NROWS * DMODEL * 2;
    u16*   Wt     = (u16*)ws;                 ws += (size_t)ZSTRIDE * DMODEL * 2;
    u16*   Wot    = (u16*)ws;                 ws += (size_t)DMODEL * DINNER * 2;
    float* zx     = (float*)ws;               ws += (size_t)NROWS * ZSTRIDE * 4;
    u16*   xsh    = (u16*)ws;                 ws += (size_t)NROWS * GNN * 2;
    u16*   Bsh    = (u16*)ws;                 ws += (size_t)NROWS * GNN * 2;
    u16*   Csh    = (u16*)ws;                 ws += (size_t)NROWS * GNN * 2;
    u16*   XT     = (u16*)ws;                 ws += (size_t)NB * GNN * LN_TOK * 2;
    u16*   BT     = (u16*)ws;                 ws += (size_t)NB * GNN * LN_TOK * 2;
    float* dtp    = (float*)ws;               ws += (size_t)NB * NHEADS * LN_TOK * 4;
    float* laa    = (float*)ws;               ws += (size_t)NB * NHEADS * LN_TOK * 4;
    float* gcum   = (float*)ws;               ws += (size_t)NB * NHEADS * LN_TOK * 4;
    u16*   Mb     = (u16*)ws;                 ws += (size_t)512 * 16384 * 2;
    u16*   states = (u16*)ws;                 ws += (size_t)512 * 16384 * 2;
    u16*   ybig   = (u16*)ws;                 ws += (size_t)NROWS * DINNER * 2;
    u16*   ybuf   = Mb;  // reuse (Mb dead after k_chunkY)

    k_ln<<<NROWS, 256, 0, stream>>>(u, ln_gamma, ln_beta, xn_b);

    k_tcast<<<dim3(ZSTRIDE / 64, DMODEL / 64), 256, 0, stream>>>(W_in, Wt, DMODEL, DPROJ, ZSTRIDE);
    k_tcast<<<dim3(DMODEL / 64, DINNER / 64), 256, 0, stream>>>(W_out, Wot, DINNER, DMODEL, DMODEL);

    k_gemm<<<dim3(ZSTRIDE / 128, NROWS / 128), 256, 0, stream>>>(xn_b, Wt, zx, DMODEL, ZSTRIDE, nullptr);

    k_conv<<<NROWS, 256, 0, stream>>>(zx, conv_w, conv_b, dt_bias, A_log, xsh, Bsh, Csh, dtp, laa);

    k_tbf<<<dim3(GNN / 64, LN_TOK / 64, NB), 256, 0, stream>>>(xsh, XT);
    k_tbf<<<dim3(GNN / 64, LN_TOK / 64, NB), 256, 0, stream>>>(Bsh, BT);

    k_prefix<<<NB * NHEADS * NCHUNK, 128, 0, stream>>>(laa, gcum);

    k_chunkM<<<NB * NHEADS * NCHUNK, 256, 0, stream>>>(Bsh, Csh, B_scale, gcum, dtp, Mb);

    k_chunkS<<<NB * NHEADS * NCHUNK, 256, 0, stream>>>(BT, XT, B_scale, gcum, dtp, states);

    k_scan<<<(NB * NHEADS * 16384) / 256, 256, 0, stream>>>(states, gcum);

    k_chunkY<<<NB * NHEADS * NCHUNK, 256, 0, stream>>>(Csh, states, Mb, XT, gcum, ybig);

    k_gate<<<NROWS, 256, 0, stream>>>(ybig, zx, xsh, D_param, rms_w, ybuf);

    k_gemm2<<<dim3(DMODEL / 64, NROWS / 128), 256, 0, stream>>>(ybuf, Wot, out, DINNER, DMODEL, u);
}

// Round 4
// 259.584 us; speedup vs baseline: 4.0373x; 1.0285x over previous
//
#include <hip/hip_runtime.h>
#include <math.h>

#define LN_TOK 4096
#define NB 2
#define NROWS (NB * LN_TOK)          // 8192
#define DMODEL 256
#define DINNER 1024
#define NHEADS 8
#define GNN 128
#define DPROJ 2312
#define ZSTRIDE 2432                 // padded in-proj N (19*128)
#define EPSF 1e-5f
#define NCHUNK 32
#define CHUNK 128
#define GPAD 72                      // LDS row stride in bf16 elems (144 B)

typedef unsigned short u16;
typedef unsigned int u32;
typedef __attribute__((ext_vector_type(8))) short shortx8;
typedef __attribute__((ext_vector_type(4))) float floatx4;

__device__ __forceinline__ float sigmoidf_(float v) { return 1.f / (1.f + __expf(-v)); }
__device__ __forceinline__ float siluf_(float v)    { return v / (1.f + __expf(-v)); }
__device__ __forceinline__ float softplusf_(float v){ return v > 20.f ? v : log1pf(__expf(v)); }
__device__ __forceinline__ float b2f(u16 h) { return __uint_as_float(((u32)h) << 16); }
__device__ __forceinline__ u16 f2b(float f) {
    u32 u = __float_as_uint(f);
    u32 r = (u + 0x7fffu + ((u >> 16) & 1u)) >> 16;
    return (u16)r;
}

// ---------------- LayerNorm -> bf16 xn ----------------
__global__ void k_ln(const float* __restrict__ u, const float* __restrict__ gam,
                     const float* __restrict__ bet, u16* __restrict__ xn) {
    int row = blockIdx.x;
    int tid = threadIdx.x;
    float v = u[(size_t)row * DMODEL + tid];
    __shared__ float s1[256], s2[256];
    s1[tid] = v; s2[tid] = v * v;
    __syncthreads();
    for (int off = 128; off > 0; off >>= 1) {
        if (tid < off) { s1[tid] += s1[tid + off]; s2[tid] += s2[tid + off]; }
        __syncthreads();
    }
    float mean = s1[0] * (1.f / DMODEL);
    float var  = s2[0] * (1.f / DMODEL) - mean * mean;
    float r = rsqrtf(var + EPSF);
    xn[(size_t)row * DMODEL + tid] = f2b((v - mean) * r * gam[tid] + bet[tid]);
}

// ---------------- transpose-cast fp32 [R][C] -> bf16 [Cp][R], zero pad rows --
__global__ void k_tcast(const float* __restrict__ in, u16* __restrict__ out,
                        int R, int C, int Cp) {
    __shared__ float tile[64][65];
    int c0 = blockIdx.x * 64, r0 = blockIdx.y * 64;
    int tx = threadIdx.x & 63, ty = threadIdx.x >> 6;
    for (int rr = ty; rr < 64; rr += 4) {
        int r = r0 + rr, c = c0 + tx;
        tile[rr][tx] = (r < R && c < C) ? in[(size_t)r * C + c] : 0.f;
    }
    __syncthreads();
    for (int cc = ty; cc < 64; cc += 4) {
        int c = c0 + cc, r = r0 + tx;
        if (c < Cp && r < R) out[(size_t)c * R + r] = f2b(tile[tx][cc]);
    }
}

// ---------------- bf16 transpose: in [b*4096+t][128] -> out [b*128+p][4096] --
__global__ void k_tbf(const u16* __restrict__ in, u16* __restrict__ out) {
    __shared__ u16 tile[64][65];
    int b = blockIdx.z;
    int p0 = blockIdx.x * 64, t0 = blockIdx.y * 64;
    int tx = threadIdx.x & 63, ty = threadIdx.x >> 6;
    for (int tt = ty; tt < 64; tt += 4)
        tile[tt][tx] = in[((size_t)(b * LN_TOK + t0 + tt)) * GNN + p0 + tx];
    __syncthreads();
    for (int pp = ty; pp < 64; pp += 4)
        out[((size_t)(b * GNN + p0 + pp)) * LN_TOK + t0 + tx] = tile[tx][pp];
}

// ---------------- bf16 MFMA GEMM (bf16 out): C = A(MxK) @ Bt(NxK)^T ----------
__global__ __launch_bounds__(256) void k_gemm_bf(const u16* __restrict__ A,
                                                 const u16* __restrict__ Bt,
                                                 u16* __restrict__ C,
                                                 int K, int ldc) {
    __shared__ u16 As[128 * GPAD];
    __shared__ u16 Bs[128 * GPAD];
    int tid = threadIdx.x;
    int wave = tid >> 6, lane = tid & 63;
    int wm = wave >> 1, wn = wave & 1;
    int quad = lane >> 4, l16 = lane & 15;
    int m0 = blockIdx.y * 128, n0 = blockIdx.x * 128;
    floatx4 acc[4][4] = {};
    for (int k0 = 0; k0 < K; k0 += 64) {
#pragma unroll
        for (int p = 0; p < 4; p++) {
            int i = p * 256 + tid;
            int row = i >> 3, kk = (i & 7) << 3;
            *(int4*)&As[row * GPAD + kk] = *(const int4*)&A[(size_t)(m0 + row) * K + k0 + kk];
            *(int4*)&Bs[row * GPAD + kk] = *(const int4*)&Bt[(size_t)(n0 + row) * K + k0 + kk];
        }
        __syncthreads();
#pragma unroll
        for (int ks = 0; ks < 64; ks += 32) {
            shortx8 af[4], bfr[4];
#pragma unroll
            for (int i = 0; i < 4; i++)
                af[i] = *(shortx8*)&As[(wm * 64 + i * 16 + l16) * GPAD + ks + (quad << 3)];
#pragma unroll
            for (int j = 0; j < 4; j++)
                bfr[j] = *(shortx8*)&Bs[(wn * 64 + j * 16 + l16) * GPAD + ks + (quad << 3)];
#pragma unroll
            for (int i = 0; i < 4; i++)
#pragma unroll
                for (int j = 0; j < 4; j++)
                    acc[i][j] = __builtin_amdgcn_mfma_f32_16x16x32_bf16(af[i], bfr[j], acc[i][j], 0, 0, 0);
        }
        __syncthreads();
    }
#pragma unroll
    for (int i = 0; i < 4; i++) {
        int row = m0 + wm * 64 + i * 16 + quad * 4;
#pragma unroll
        for (int j = 0; j < 4; j++) {
            int col = n0 + wn * 64 + j * 16 + l16;
#pragma unroll
            for (int r = 0; r < 4; r++)
                C[(size_t)(row + r) * ldc + col] = f2b(acc[i][j][r]);
        }
    }
}

// ---------------- bf16 MFMA GEMM variant: 128x64 tile, fp32 out + residual ---
__global__ __launch_bounds__(256) void k_gemm2(const u16* __restrict__ A,
                                               const u16* __restrict__ Bt,
                                               float* __restrict__ C,
                                               int K, int ldc,
                                               const float* __restrict__ addC) {
    __shared__ u16 As[128 * GPAD];
    __shared__ u16 Bs[64 * GPAD];
    int tid = threadIdx.x;
    int wave = tid >> 6, lane = tid & 63;
    int wm = wave >> 1, wn = wave & 1;
    int quad = lane >> 4, l16 = lane & 15;
    int m0 = blockIdx.y * 128, n0 = blockIdx.x * 64;
    floatx4 acc[4][2] = {};
    for (int k0 = 0; k0 < K; k0 += 64) {
#pragma unroll
        for (int p = 0; p < 4; p++) {
            int i = p * 256 + tid;
            int row = i >> 3, kk = (i & 7) << 3;
            *(int4*)&As[row * GPAD + kk] = *(const int4*)&A[(size_t)(m0 + row) * K + k0 + kk];
        }
#pragma unroll
        for (int p = 0; p < 2; p++) {
            int i = p * 256 + tid;
            int row = i >> 3, kk = (i & 7) << 3;
            *(int4*)&Bs[row * GPAD + kk] = *(const int4*)&Bt[(size_t)(n0 + row) * K + k0 + kk];
        }
        __syncthreads();
#pragma unroll
        for (int ks = 0; ks < 64; ks += 32) {
            shortx8 af[4], bfr[2];
#pragma unroll
            for (int i = 0; i < 4; i++)
                af[i] = *(shortx8*)&As[(wm * 64 + i * 16 + l16) * GPAD + ks + (quad << 3)];
#pragma unroll
            for (int j = 0; j < 2; j++)
                bfr[j] = *(shortx8*)&Bs[(wn * 32 + j * 16 + l16) * GPAD + ks + (quad << 3)];
#pragma unroll
            for (int i = 0; i < 4; i++)
#pragma unroll
                for (int j = 0; j < 2; j++)
                    acc[i][j] = __builtin_amdgcn_mfma_f32_16x16x32_bf16(af[i], bfr[j], acc[i][j], 0, 0, 0);
        }
        __syncthreads();
    }
#pragma unroll
    for (int i = 0; i < 4; i++) {
        int row = m0 + wm * 64 + i * 16 + quad * 4;
#pragma unroll
        for (int j = 0; j < 2; j++) {
            int col = n0 + wn * 32 + j * 16 + l16;
#pragma unroll
            for (int r = 0; r < 4; r++) {
                size_t idx = (size_t)(row + r) * ldc + col;
                float v = acc[i][j][r];
                if (addC) v += addC[idx];
                C[idx] = v;
            }
        }
    }
}

// ------- sliding-window conv(K=4) + SiLU + splits + dt prep (bf16 zx) --------
// one block per 32-token strip; thread owns channels tid+256k (k=0..4)
__global__ __launch_bounds__(256) void k_conv(const u16* __restrict__ zxb,
                                              const float* __restrict__ cw,
                                              const float* __restrict__ cb,
                                              const float* __restrict__ dt_bias,
                                              const float* __restrict__ A_log,
                                              u16* __restrict__ xsh, u16* __restrict__ Bsh,
                                              u16* __restrict__ Csh, float* __restrict__ dtp,
                                              float* __restrict__ laa) {
    int blk = blockIdx.x;                  // NROWS/32 = 256 blocks
    int b = blk >> 7, tile = blk & 127;
    int t0 = tile * 32;
    int tid = threadIdx.x;
    __shared__ float sv[256];

    float w[5][4], bias[5];
#pragma unroll
    for (int k = 0; k < 5; k++) {
        int c = tid + 256 * k;
#pragma unroll
        for (int j = 0; j < 4; j++) w[k][j] = cw[c * 4 + j];
        bias[k] = cb[c];
    }
    float dtb = 0.f, negA = 0.f;
    if (tid < NHEADS) { dtb = dt_bias[tid]; negA = -__expf(A_log[tid]); }

    // history: value at t-1, t-2, t-3 per channel
    float h1[5], h2[5], h3[5];
#pragma unroll
    for (int k = 0; k < 5; k++) {
        int c = tid + 256 * k;
        size_t base = ((size_t)b * LN_TOK) * ZSTRIDE + DINNER + c;
        h3[k] = (t0 >= 3) ? b2f(zxb[base + (size_t)(t0 - 3) * ZSTRIDE]) : 0.f;
        h2[k] = (t0 >= 2) ? b2f(zxb[base + (size_t)(t0 - 2) * ZSTRIDE]) : 0.f;
        h1[k] = (t0 >= 1) ? b2f(zxb[base + (size_t)(t0 - 1) * ZSTRIDE]) : 0.f;
    }

    for (int t = t0; t < t0 + 32; t++) {
        size_t zrow = ((size_t)(b * LN_TOK + t)) * ZSTRIDE;
        size_t rowp = (size_t)(b * LN_TOK + t) * GNN;
        float xpart = 0.f;
#pragma unroll
        for (int k = 0; k < 5; k++) {
            float cur = b2f(zxb[zrow + DINNER + tid + 256 * k]);
            float conv = bias[k] + w[k][3] * cur + w[k][2] * h1[k] + w[k][1] * h2[k] + w[k][0] * h3[k];
            h3[k] = h2[k]; h2[k] = h1[k]; h1[k] = cur;
            float s = siluf_(conv);
            if (k < 4) xpart += s;
            else {
                if (tid < 128) Bsh[rowp + tid] = f2b(s);
                else           Csh[rowp + tid - 128] = f2b(s);
            }
        }
        sv[tid] = xpart;
        __syncthreads();
        if (tid < 128)
            xsh[rowp + tid] = f2b((sv[tid] + sv[tid + 128]) * 0.125f);
        if (tid < NHEADS) {
            float dtv = b2f(zxb[zrow + 2304 + tid]) + dtb;
            float dp = softplusf_(dtv);
            size_t idx = ((size_t)(b * NHEADS + tid)) * LN_TOK + t;
            dtp[idx] = dp;
            laa[idx] = negA * dp;
        }
        __syncthreads();
    }
}

// ---------------- per-chunk inclusive prefix sum of log-decay ----------------
__global__ void k_prefix(const float* __restrict__ laa, float* __restrict__ gcum) {
    int blk = blockIdx.x;
    int bh = blk / NCHUNK, c = blk % NCHUNK;
    int tid = threadIdx.x;
    __shared__ float s[128];
    size_t base = (size_t)bh * LN_TOK + c * CHUNK;
    s[tid] = laa[base + tid];
    __syncthreads();
    for (int off = 1; off < 128; off <<= 1) {
        float v = (tid >= off) ? s[tid - off] : 0.f;
        __syncthreads();
        s[tid] += v;
        __syncthreads();
    }
    gcum[base + tid] = s[tid];
}

// ---------------- chunkM (MFMA): Mb[t][s] = mask*exp(g_t-g_s)*dt_s*(B'_s.C_t)
__global__ __launch_bounds__(256) void k_chunkM(const u16* __restrict__ Bsh,
                                                const u16* __restrict__ Csh,
                                                const float* __restrict__ scale,
                                                const float* __restrict__ gcum,
                                                const float* __restrict__ dtp,
                                                u16* __restrict__ Mb) {
    int blk = blockIdx.x;
    int c = blk & 31, h = (blk >> 5) & 7, b = blk >> 8;
    int t0 = c * CHUNK;
    __shared__ u16 As[128 * GPAD];
    __shared__ u16 Bs[128 * GPAD];
    __shared__ float g[128], dts[128], sc[128];
    int tid = threadIdx.x;
    int wave = tid >> 6, lane = tid & 63;
    int wm = wave >> 1, wn = wave & 1;
    int quad = lane >> 4, l16 = lane & 15;
    size_t bhbase = (size_t)(b * NHEADS + h) * LN_TOK + t0;
    if (tid < 128) {
        g[tid] = gcum[bhbase + tid];
        dts[tid] = dtp[bhbase + tid];
        sc[tid] = scale[h * GNN + tid];
    }
    __syncthreads();
    floatx4 acc[4][4] = {};
    size_t rbase = (size_t)(b * LN_TOK + t0) * GNN;   // token rows
    for (int k0 = 0; k0 < 128; k0 += 64) {
#pragma unroll
        for (int p = 0; p < 4; p++) {
            int i = p * 256 + tid;
            int row = i >> 3, kk = (i & 7) << 3;
            int4 raw = *(const int4*)&Bsh[rbase + (size_t)row * GNN + k0 + kk];
            u16* rp = (u16*)&raw;
            u32 w[4];
#pragma unroll
            for (int q = 0; q < 4; q++) {
                u16 a  = f2b(b2f(rp[2 * q])     * sc[k0 + kk + 2 * q]);
                u16 bb = f2b(b2f(rp[2 * q + 1]) * sc[k0 + kk + 2 * q + 1]);
                w[q] = (u32)a | ((u32)bb << 16);
            }
            *(int4*)&As[row * GPAD + kk] = make_int4(w[0], w[1], w[2], w[3]);
            *(int4*)&Bs[row * GPAD + kk] = *(const int4*)&Csh[rbase + (size_t)row * GNN + k0 + kk];
        }
        __syncthreads();
#pragma unroll
        for (int ks = 0; ks < 64; ks += 32) {
            shortx8 af[4], bfr[4];
#pragma unroll
            for (int i = 0; i < 4; i++)
                af[i] = *(shortx8*)&As[(wm * 64 + i * 16 + l16) * GPAD + ks + (quad << 3)];
#pragma unroll
            for (int j = 0; j < 4; j++)
                bfr[j] = *(shortx8*)&Bs[(wn * 64 + j * 16 + l16) * GPAD + ks + (quad << 3)];
#pragma unroll
            for (int i = 0; i < 4; i++)
#pragma unroll
                for (int j = 0; j < 4; j++)
                    acc[i][j] = __builtin_amdgcn_mfma_f32_16x16x32_bf16(af[i], bfr[j], acc[i][j], 0, 0, 0);
        }
        __syncthreads();
    }
    size_t mb = (size_t)blk * (CHUNK * CHUNK);
#pragma unroll
    for (int i = 0; i < 4; i++) {
        int s0 = wm * 64 + i * 16 + quad * 4;
#pragma unroll
        for (int j = 0; j < 4; j++) {
            int t = wn * 64 + j * 16 + l16;
            u16 o[4];
#pragma unroll
            for (int r = 0; r < 4; r++) {
                int s = s0 + r;
                float v = (s <= t) ? acc[i][j][r] * __expf(g[t] - g[s]) * dts[s] : 0.f;
                o[r] = f2b(v);
            }
            u32 lo = (u32)o[0] | ((u32)o[1] << 16);
            u32 hi = (u32)o[2] | ((u32)o[3] << 16);
            *(uint2*)&Mb[mb + (size_t)t * CHUNK + s0] = make_uint2(lo, hi);
        }
    }
}

// ---------------- chunkS (MFMA): states[p][n] = sum_s XT[p][s]*BT[n][s]*sc*esc
__global__ __launch_bounds__(256) void k_chunkS(const u16* __restrict__ BT,
                                                const u16* __restrict__ XT,
                                                const float* __restrict__ scale,
                                                const float* __restrict__ gcum,
                                                const float* __restrict__ dtp,
                                                u16* __restrict__ states) {
    int blk = blockIdx.x;
    int c = blk & 31, h = (blk >> 5) & 7, b = blk >> 8;
    int t0 = c * CHUNK;
    __shared__ u16 As[128 * GPAD];
    __shared__ u16 Bs[128 * GPAD];
    __shared__ float esc[128], scl[128];
    int tid = threadIdx.x;
    int wave = tid >> 6, lane = tid & 63;
    int wm = wave >> 1, wn = wave & 1;
    int quad = lane >> 4, l16 = lane & 15;
    size_t bhbase = (size_t)(b * NHEADS + h) * LN_TOK + t0;
    if (tid < 128) {
        float gl = gcum[bhbase + 127];
        esc[tid] = __expf(gl - gcum[bhbase + tid]) * dtp[bhbase + tid];
        scl[tid] = scale[h * GNN + tid];
    }
    __syncthreads();
    floatx4 acc[4][4] = {};
    size_t tbase = (size_t)(b * GNN) * LN_TOK + t0;
    for (int k0 = 0; k0 < 128; k0 += 64) {
#pragma unroll
        for (int p = 0; p < 4; p++) {
            int i = p * 256 + tid;
            int row = i >> 3, kk = (i & 7) << 3;
            int4 raw = *(const int4*)&BT[tbase + (size_t)row * LN_TOK + k0 + kk];
            u16* rp = (u16*)&raw;
            float sr = scl[row];
            u32 w[4];
#pragma unroll
            for (int q = 0; q < 4; q++) {
                u16 a  = f2b(b2f(rp[2 * q])     * sr * esc[k0 + kk + 2 * q]);
                u16 bb = f2b(b2f(rp[2 * q + 1]) * sr * esc[k0 + kk + 2 * q + 1]);
                w[q] = (u32)a | ((u32)bb << 16);
            }
            *(int4*)&As[row * GPAD + kk] = make_int4(w[0], w[1], w[2], w[3]);
            *(int4*)&Bs[row * GPAD + kk] = *(const int4*)&XT[tbase + (size_t)row * LN_TOK + k0 + kk];
        }
        __syncthreads();
#pragma unroll
        for (int ks = 0; ks < 64; ks += 32) {
            shortx8 af[4], bfr[4];
#pragma unroll
            for (int i = 0; i < 4; i++)
                af[i] = *(shortx8*)&As[(wm * 64 + i * 16 + l16) * GPAD + ks + (quad << 3)];
#pragma unroll
            for (int j = 0; j < 4; j++)
                bfr[j] = *(shortx8*)&Bs[(wn * 64 + j * 16 + l16) * GPAD + ks + (quad << 3)];
#pragma unroll
            for (int i = 0; i < 4; i++)
#pragma unroll
                for (int j = 0; j < 4; j++)
                    acc[i][j] = __builtin_amdgcn_mfma_f32_16x16x32_bf16(af[i], bfr[j], acc[i][j], 0, 0, 0);
        }
        __syncthreads();
    }
    size_t sbase = (size_t)blk * 16384;
#pragma unroll
    for (int i = 0; i < 4; i++) {
        int n0 = wm * 64 + i * 16 + quad * 4;
#pragma unroll
        for (int j = 0; j < 4; j++) {
            int p = wn * 64 + j * 16 + l16;
            u16 o[4];
#pragma unroll
            for (int r = 0; r < 4; r++) o[r] = f2b(acc[i][j][r]);
            u32 lo = (u32)o[0] | ((u32)o[1] << 16);
            u32 hi = (u32)o[2] | ((u32)o[3] << 16);
            *(uint2*)&states[sbase + (size_t)p * CHUNK + n0] = make_uint2(lo, hi);
        }
    }
}

// ---------------- inter-chunk scan (in-place, bf16 storage) ------------------
__global__ void k_scan(u16* __restrict__ states, const float* __restrict__ gcum) {
    int idx = blockIdx.x * 256 + threadIdx.x;
    int bh = idx >> 14;
    int np = idx & 16383;
    float run = 0.f;
    size_t base = (size_t)bh * NCHUNK * 16384 + np;
    size_t gb = (size_t)bh * LN_TOK;
    for (int c = 0; c < NCHUNK; c++) {
        float G = __expf(gcum[gb + c * CHUNK + 127]);
        float l = b2f(states[base + (size_t)c * 16384]);
        states[base + (size_t)c * 16384] = f2b(run);
        run = G * run + l;
    }
}

// ---------------- chunkY (MFMA): y = eg[t]*C @ S0^T + Mb @ X^T (bf16 out) ----
__global__ __launch_bounds__(256) void k_chunkY(const u16* __restrict__ Csh,
                                                const u16* __restrict__ states,
                                                const u16* __restrict__ Mb,
                                                const u16* __restrict__ XT,
                                                const float* __restrict__ gcum,
                                                u16* __restrict__ y) {
    int blk = blockIdx.x;
    int c = blk & 31, h = (blk >> 5) & 7, b = blk >> 8;
    int t0 = c * CHUNK;
    __shared__ u16 As[128 * GPAD];
    __shared__ u16 Bs[128 * GPAD];
    __shared__ float eg[128];
    int tid = threadIdx.x;
    int wave = tid >> 6, lane = tid & 63;
    int wm = wave >> 1, wn = wave & 1;
    int quad = lane >> 4, l16 = lane & 15;
    size_t bhbase = (size_t)(b * NHEADS + h) * LN_TOK + t0;
    if (tid < 128) eg[tid] = __expf(gcum[bhbase + tid]);
    __syncthreads();
    floatx4 acc[4][4] = {};
    size_t crow = (size_t)(b * LN_TOK + t0) * GNN;
    size_t sbase = (size_t)blk * 16384;
    size_t mbase = (size_t)blk * 16384;
    size_t xtb = (size_t)(b * GNN) * LN_TOK + t0;
    // phase 1: K = n (eg[t]*Csh, states[p][n] bf16)
    for (int k0 = 0; k0 < 128; k0 += 64) {
#pragma unroll
        for (int p = 0; p < 4; p++) {
            int i = p * 256 + tid;
            int row = i >> 3, kk = (i & 7) << 3;
            int4 raw = *(const int4*)&Csh[crow + (size_t)row * GNN + k0 + kk];
            float e = eg[row];
            u16* rp = (u16*)&raw;
            u32 w[4];
#pragma unroll
            for (int q = 0; q < 4; q++) {
                u16 a  = f2b(b2f(rp[2 * q]) * e);
                u16 bb = f2b(b2f(rp[2 * q + 1]) * e);
                w[q] = (u32)a | ((u32)bb << 16);
            }
            *(int4*)&As[row * GPAD + kk] = make_int4(w[0], w[1], w[2], w[3]);
            *(int4*)&Bs[row * GPAD + kk] = *(const int4*)&states[sbase + (size_t)row * CHUNK + k0 + kk];
        }
        __syncthreads();
#pragma unroll
        for (int ks = 0; ks < 64; ks += 32) {
            shortx8 af[4], bfr[4];
#pragma unroll
            for (int i = 0; i < 4; i++)
                af[i] = *(shortx8*)&As[(wm * 64 + i * 16 + l16) * GPAD + ks + (quad << 3)];
#pragma unroll
            for (int j = 0; j < 4; j++)
                bfr[j] = *(shortx8*)&Bs[(wn * 64 + j * 16 + l16) * GPAD + ks + (quad << 3)];
#pragma unroll
            for (int i = 0; i < 4; i++)
#pragma unroll
                for (int j = 0; j < 4; j++)
                    acc[i][j] = __builtin_amdgcn_mfma_f32_16x16x32_bf16(af[i], bfr[j], acc[i][j], 0, 0, 0);
        }
        __syncthreads();
    }
    // phase 2: K = s (Mb[t][s], XT[p][s])
    for (int k0 = 0; k0 < 128; k0 += 64) {
#pragma unroll
        for (int p = 0; p < 4; p++) {
            int i = p * 256 + tid;
            int row = i >> 3, kk = (i & 7) << 3;
            *(int4*)&As[row * GPAD + kk] = *(const int4*)&Mb[mbase + (size_t)row * CHUNK + k0 + kk];
            *(int4*)&Bs[row * GPAD + kk] = *(const int4*)&XT[xtb + (size_t)row * LN_TOK + k0 + kk];
        }
        __syncthreads();
#pragma unroll
        for (int ks = 0; ks < 64; ks += 32) {
            shortx8 af[4], bfr[4];
#pragma unroll
            for (int i = 0; i < 4; i++)
                af[i] = *(shortx8*)&As[(wm * 64 + i * 16 + l16) * GPAD + ks + (quad << 3)];
#pragma unroll
            for (int j = 0; j < 4; j++)
                bfr[j] = *(shortx8*)&Bs[(wn * 64 + j * 16 + l16) * GPAD + ks + (quad << 3)];
#pragma unroll
            for (int i = 0; i < 4; i++)
#pragma unroll
                for (int j = 0; j < 4; j++)
                    acc[i][j] = __builtin_amdgcn_mfma_f32_16x16x32_bf16(af[i], bfr[j], acc[i][j], 0, 0, 0);
        }
        __syncthreads();
    }
#pragma unroll
    for (int i = 0; i < 4; i++) {
        int t = wm * 64 + i * 16 + quad * 4;
#pragma unroll
        for (int j = 0; j < 4; j++) {
            int p = wn * 64 + j * 16 + l16;
#pragma unroll
            for (int r = 0; r < 4; r++)
                y[((size_t)(b * LN_TOK + t0 + t + r)) * DINNER + h * GNN + p] = f2b(acc[i][j][r]);
        }
    }
}

// ---------------- gating + D*x + RMSNorm -> bf16 ybuf ------------------------
__global__ void k_gate(const u16* __restrict__ y, const u16* __restrict__ zxb,
                       const u16* __restrict__ xsh, const float* __restrict__ Dp,
                       const float* __restrict__ rw, u16* __restrict__ ybuf) {
    int row = blockIdx.x;
    int tid = threadIdx.x;
    size_t yb = (size_t)row * DINNER;
    size_t zb = (size_t)row * ZSTRIDE;
    size_t xb = (size_t)row * GNN;
    float yg[4];
    float ss = 0.f;
#pragma unroll
    for (int q = 0; q < 4; q++) {
        int k = tid * 4 + q;
        int h = k >> 7, p = k & 127;
        float z = b2f(zxb[zb + k]);
        float v = (b2f(y[yb + k]) + Dp[h] * b2f(xsh[xb + p])) * z * sigmoidf_(z);
        yg[q] = v;
        ss += v * v;
    }
    __shared__ float red[256];
    red[tid] = ss;
    __syncthreads();
    for (int off = 128; off > 0; off >>= 1) {
        if (tid < off) red[tid] += red[tid + off];
        __syncthreads();
    }
    float scale = rsqrtf(red[0] * (1.f / DINNER) + EPSF);
#pragma unroll
    for (int q = 0; q < 4; q++) {
        int k = tid * 4 + q;
        ybuf[yb + k] = f2b(yg[q] * scale * rw[k]);
    }
}

extern "C" void kernel_launch(void* const* d_in, const int* in_sizes, int n_in,
                              void* d_out, int out_size, void* d_ws, size_t ws_size,
                              hipStream_t stream) {
    (void)in_sizes; (void)n_in; (void)out_size; (void)ws_size;
    const float* u        = (const float*)d_in[0];
    const float* ln_gamma = (const float*)d_in[1];
    const float* ln_beta  = (const float*)d_in[2];
    const float* W_in     = (const float*)d_in[3];
    const float* conv_w   = (const float*)d_in[4];
    const float* conv_b   = (const float*)d_in[5];
    const float* dt_bias  = (const float*)d_in[6];
    const float* A_log    = (const float*)d_in[7];
    const float* D_param  = (const float*)d_in[8];
    const float* B_scale  = (const float*)d_in[9];
    const float* rms_w    = (const float*)d_in[10];
    const float* W_out    = (const float*)d_in[11];
    float* out = (float*)d_out;

    char* ws = (char*)d_ws;
    u16*   xn_b   = (u16*)ws;                 ws += (size_t)NROWS * DMODEL * 2;
    u16*   Wt     = (u16*)ws;                 ws += (size_t)ZSTRIDE * DMODEL * 2;
    u16*   Wot    = (u16*)ws;                 ws += (size_t)DMODEL * DINNER * 2;
    u16*   zxb    = (u16*)ws;                 ws += (size_t)NROWS * ZSTRIDE * 2;
    u16*   xsh    = (u16*)ws;                 ws += (size_t)NROWS * GNN * 2;
    u16*   Bsh    = (u16*)ws;                 ws += (size_t)NROWS * GNN * 2;
    u16*   Csh    = (u16*)ws;                 ws += (size_t)NROWS * GNN * 2;
    u16*   XT     = (u16*)ws;                 ws += (size_t)NB * GNN * LN_TOK * 2;
    u16*   BT     = (u16*)ws;                 ws += (size_t)NB * GNN * LN_TOK * 2;
    float* dtp    = (float*)ws;               ws += (size_t)NB * NHEADS * LN_TOK * 4;
    float* laa    = (float*)ws;               ws += (size_t)NB * NHEADS * LN_TOK * 4;
    float* gcum   = (float*)ws;               ws += (size_t)NB * NHEADS * LN_TOK * 4;
    u16*   Mb     = (u16*)ws;                 ws += (size_t)512 * 16384 * 2;
    u16*   states = (u16*)ws;                 ws += (size_t)512 * 16384 * 2;
    u16*   ybig   = (u16*)ws;                 ws += (size_t)NROWS * DINNER * 2;
    u16*   ybuf   = Mb;  // reuse (Mb dead after k_chunkY)

    k_ln<<<NROWS, 256, 0, stream>>>(u, ln_gamma, ln_beta, xn_b);

    k_tcast<<<dim3(ZSTRIDE / 64, DMODEL / 64), 256, 0, stream>>>(W_in, Wt, DMODEL, DPROJ, ZSTRIDE);
    k_tcast<<<dim3(DMODEL / 64, DINNER / 64), 256, 0, stream>>>(W_out, Wot, DINNER, DMODEL, DMODEL);

    k_gemm_bf<<<dim3(ZSTRIDE / 128, NROWS / 128), 256, 0, stream>>>(xn_b, Wt, zxb, DMODEL, ZSTRIDE);

    k_conv<<<NROWS / 32, 256, 0, stream>>>(zxb, conv_w, conv_b, dt_bias, A_log, xsh, Bsh, Csh, dtp, laa);

    k_tbf<<<dim3(GNN / 64, LN_TOK / 64, NB), 256, 0, stream>>>(xsh, XT);
    k_tbf<<<dim3(GNN / 64, LN_TOK / 64, NB), 256, 0, stream>>>(Bsh, BT);

    k_prefix<<<NB * NHEADS * NCHUNK, 128, 0, stream>>>(laa, gcum);

    k_chunkM<<<NB * NHEADS * NCHUNK, 256, 0, stream>>>(Bsh, Csh, B_scale, gcum, dtp, Mb);

    k_chunkS<<<NB * NHEADS * NCHUNK, 256, 0, stream>>>(BT, XT, B_scale, gcum, dtp, states);

    k_scan<<<(NB * NHEADS * 16384) / 256, 256, 0, stream>>>(states, gcum);

    k_chunkY<<<NB * NHEADS * NCHUNK, 256, 0, stream>>>(Csh, states, Mb, XT, gcum, ybig);

    k_gate<<<NROWS, 256, 0, stream>>>(ybig, zxb, xsh, D_param, rms_w, ybuf);

    k_gemm2<<<dim3(DMODEL / 64, NROWS / 128), 256, 0, stream>>>(ybuf, Wot, out, DINNER, DMODEL, u);
}

// Round 5
// 224.498 us; speedup vs baseline: 4.6682x; 1.1563x over previous
//
#include <hip/hip_runtime.h>
#include <math.h>

#define LN_TOK 4096
#define NB 2
#define NROWS (NB * LN_TOK)          // 8192
#define DMODEL 256
#define DINNER 1024
#define NHEADS 8
#define GNN 128
#define DPROJ 2312
#define ZSTRIDE 2432                 // padded in-proj N (19*128)
#define EPSF 1e-5f
#define NCHUNK 32
#define CHUNK 128
#define GPAD 72                      // LDS row stride in bf16 elems (144 B)
#define TT 16                        // conv tokens per block

typedef unsigned short u16;
typedef unsigned int u32;
typedef __attribute__((ext_vector_type(8))) short shortx8;
typedef __attribute__((ext_vector_type(4))) float floatx4;

__device__ __forceinline__ float sigmoidf_(float v) { return 1.f / (1.f + __expf(-v)); }
__device__ __forceinline__ float siluf_(float v)    { return v / (1.f + __expf(-v)); }
__device__ __forceinline__ float softplusf_(float v){ return v > 20.f ? v : log1pf(__expf(v)); }
__device__ __forceinline__ float b2f(u16 h) { return __uint_as_float(((u32)h) << 16); }
__device__ __forceinline__ u16 f2b(float f) {
    u32 u = __float_as_uint(f);
    u32 r = (u + 0x7fffu + ((u >> 16) & 1u)) >> 16;
    return (u16)r;
}

// ---------------- LayerNorm -> bf16 xn ----------------
__global__ void k_ln(const float* __restrict__ u, const float* __restrict__ gam,
                     const float* __restrict__ bet, u16* __restrict__ xn) {
    int row = blockIdx.x;
    int tid = threadIdx.x;
    float v = u[(size_t)row * DMODEL + tid];
    __shared__ float s1[256], s2[256];
    s1[tid] = v; s2[tid] = v * v;
    __syncthreads();
    for (int off = 128; off > 0; off >>= 1) {
        if (tid < off) { s1[tid] += s1[tid + off]; s2[tid] += s2[tid + off]; }
        __syncthreads();
    }
    float mean = s1[0] * (1.f / DMODEL);
    float var  = s2[0] * (1.f / DMODEL) - mean * mean;
    float r = rsqrtf(var + EPSF);
    xn[(size_t)row * DMODEL + tid] = f2b((v - mean) * r * gam[tid] + bet[tid]);
}

// ---------------- transpose-cast fp32 [R][C] -> bf16 [Cp][R], zero pad rows --
__global__ void k_tcast(const float* __restrict__ in, u16* __restrict__ out,
                        int R, int C, int Cp) {
    __shared__ float tile[64][65];
    int c0 = blockIdx.x * 64, r0 = blockIdx.y * 64;
    int tx = threadIdx.x & 63, ty = threadIdx.x >> 6;
    for (int rr = ty; rr < 64; rr += 4) {
        int r = r0 + rr, c = c0 + tx;
        tile[rr][tx] = (r < R && c < C) ? in[(size_t)r * C + c] : 0.f;
    }
    __syncthreads();
    for (int cc = ty; cc < 64; cc += 4) {
        int c = c0 + cc, r = r0 + tx;
        if (c < Cp && r < R) out[(size_t)c * R + r] = f2b(tile[tx][cc]);
    }
}

// ---------------- bf16 MFMA GEMM (bf16 out): C = A(MxK) @ Bt(NxK)^T ----------
__global__ __launch_bounds__(256) void k_gemm_bf(const u16* __restrict__ A,
                                                 const u16* __restrict__ Bt,
                                                 u16* __restrict__ C,
                                                 int K, int ldc) {
    __shared__ u16 As[128 * GPAD];
    __shared__ u16 Bs[128 * GPAD];
    int tid = threadIdx.x;
    int wave = tid >> 6, lane = tid & 63;
    int wm = wave >> 1, wn = wave & 1;
    int quad = lane >> 4, l16 = lane & 15;
    int m0 = blockIdx.y * 128, n0 = blockIdx.x * 128;
    floatx4 acc[4][4] = {};
    for (int k0 = 0; k0 < K; k0 += 64) {
#pragma unroll
        for (int p = 0; p < 4; p++) {
            int i = p * 256 + tid;
            int row = i >> 3, kk = (i & 7) << 3;
            *(int4*)&As[row * GPAD + kk] = *(const int4*)&A[(size_t)(m0 + row) * K + k0 + kk];
            *(int4*)&Bs[row * GPAD + kk] = *(const int4*)&Bt[(size_t)(n0 + row) * K + k0 + kk];
        }
        __syncthreads();
#pragma unroll
        for (int ks = 0; ks < 64; ks += 32) {
            shortx8 af[4], bfr[4];
#pragma unroll
            for (int i = 0; i < 4; i++)
                af[i] = *(shortx8*)&As[(wm * 64 + i * 16 + l16) * GPAD + ks + (quad << 3)];
#pragma unroll
            for (int j = 0; j < 4; j++)
                bfr[j] = *(shortx8*)&Bs[(wn * 64 + j * 16 + l16) * GPAD + ks + (quad << 3)];
#pragma unroll
            for (int i = 0; i < 4; i++)
#pragma unroll
                for (int j = 0; j < 4; j++)
                    acc[i][j] = __builtin_amdgcn_mfma_f32_16x16x32_bf16(af[i], bfr[j], acc[i][j], 0, 0, 0);
        }
        __syncthreads();
    }
#pragma unroll
    for (int i = 0; i < 4; i++) {
        int row = m0 + wm * 64 + i * 16 + quad * 4;
#pragma unroll
        for (int j = 0; j < 4; j++) {
            int col = n0 + wn * 64 + j * 16 + l16;
#pragma unroll
            for (int r = 0; r < 4; r++)
                C[(size_t)(row + r) * ldc + col] = f2b(acc[i][j][r]);
        }
    }
}

// ---------------- bf16 MFMA GEMM variant: 128x64 tile, fp32 out + residual ---
__global__ __launch_bounds__(256) void k_gemm2(const u16* __restrict__ A,
                                               const u16* __restrict__ Bt,
                                               float* __restrict__ C,
                                               int K, int ldc,
                                               const float* __restrict__ addC) {
    __shared__ u16 As[128 * GPAD];
    __shared__ u16 Bs[64 * GPAD];
    int tid = threadIdx.x;
    int wave = tid >> 6, lane = tid & 63;
    int wm = wave >> 1, wn = wave & 1;
    int quad = lane >> 4, l16 = lane & 15;
    int m0 = blockIdx.y * 128, n0 = blockIdx.x * 64;
    floatx4 acc[4][2] = {};
    for (int k0 = 0; k0 < K; k0 += 64) {
#pragma unroll
        for (int p = 0; p < 4; p++) {
            int i = p * 256 + tid;
            int row = i >> 3, kk = (i & 7) << 3;
            *(int4*)&As[row * GPAD + kk] = *(const int4*)&A[(size_t)(m0 + row) * K + k0 + kk];
        }
#pragma unroll
        for (int p = 0; p < 2; p++) {
            int i = p * 256 + tid;
            int row = i >> 3, kk = (i & 7) << 3;
            *(int4*)&Bs[row * GPAD + kk] = *(const int4*)&Bt[(size_t)(n0 + row) * K + k0 + kk];
        }
        __syncthreads();
#pragma unroll
        for (int ks = 0; ks < 64; ks += 32) {
            shortx8 af[4], bfr[2];
#pragma unroll
            for (int i = 0; i < 4; i++)
                af[i] = *(shortx8*)&As[(wm * 64 + i * 16 + l16) * GPAD + ks + (quad << 3)];
#pragma unroll
            for (int j = 0; j < 2; j++)
                bfr[j] = *(shortx8*)&Bs[(wn * 32 + j * 16 + l16) * GPAD + ks + (quad << 3)];
#pragma unroll
            for (int i = 0; i < 4; i++)
#pragma unroll
                for (int j = 0; j < 2; j++)
                    acc[i][j] = __builtin_amdgcn_mfma_f32_16x16x32_bf16(af[i], bfr[j], acc[i][j], 0, 0, 0);
        }
        __syncthreads();
    }
#pragma unroll
    for (int i = 0; i < 4; i++) {
        int row = m0 + wm * 64 + i * 16 + quad * 4;
#pragma unroll
        for (int j = 0; j < 2; j++) {
            int col = n0 + wn * 32 + j * 16 + l16;
#pragma unroll
            for (int r = 0; r < 4; r++) {
                size_t idx = (size_t)(row + r) * ldc + col;
                float v = acc[i][j][r];
                if (addC) v += addC[idx];
                C[idx] = v;
            }
        }
    }
}

// ------- conv(K=4) + SiLU + splits + dt prep + fused XT/BT transposes --------
// one block per TT=16-token strip; LDS-staged slab, fully parallel loads.
// thread tid: x channels (tid>>7)*512+(tid&127)+128k (k=0..3), B/C channel 1024+tid
#define LDW 1296                     // LDS row stride for slab (1288 + 8)
__global__ __launch_bounds__(256) void k_conv(const u16* __restrict__ zxb,
                                              const float* __restrict__ cw,
                                              const float* __restrict__ cb,
                                              const float* __restrict__ dt_bias,
                                              const float* __restrict__ A_log,
                                              u16* __restrict__ xsh, u16* __restrict__ Bsh,
                                              u16* __restrict__ Csh, u16* __restrict__ XT,
                                              u16* __restrict__ BT,
                                              float* __restrict__ dtp, float* __restrict__ laa) {
    int blk = blockIdx.x;                  // NROWS/TT = 512 blocks
    int b = blk / (LN_TOK / TT), tile = blk % (LN_TOK / TT);
    int t0 = tile * TT;
    int tid = threadIdx.x;
    __shared__ u16 ld[(TT + 3) * LDW];
    __shared__ float sv[TT][260];
    __shared__ u16 bcv[TT][132];

    // bulk stage: rows t0-3 .. t0+TT-1, channels DINNER..DINNER+1288
    for (int i = tid; i < (TT + 3) * 161; i += 256) {
        int r = i / 161, ch = (i % 161) * 8;
        int t = t0 - 3 + r;
        int4 v = make_int4(0, 0, 0, 0);
        if (t >= 0)
            v = *(const int4*)&zxb[((size_t)(b * LN_TOK + t)) * ZSTRIDE + DINNER + ch];
        *(int4*)&ld[r * LDW + ch] = v;
    }

    int cmap[5];
#pragma unroll
    for (int k = 0; k < 4; k++) cmap[k] = (tid >> 7) * 512 + (tid & 127) + 128 * k;
    cmap[4] = 1024 + tid;
    float w0[5], w1[5], w2[5], w3[5], bias[5];
#pragma unroll
    for (int k = 0; k < 5; k++) {
        int c = cmap[k];
        w0[k] = cw[c * 4 + 0]; w1[k] = cw[c * 4 + 1];
        w2[k] = cw[c * 4 + 2]; w3[k] = cw[c * 4 + 3];
        bias[k] = cb[c];
    }
    float dtb = 0.f, negA = 0.f;
    if (tid < NHEADS) { dtb = dt_bias[tid]; negA = -__expf(A_log[tid]); }

    __syncthreads();

    float h1[5], h2[5], h3[5];
#pragma unroll
    for (int k = 0; k < 5; k++) {
        h3[k] = b2f(ld[0 * LDW + cmap[k]]);
        h2[k] = b2f(ld[1 * LDW + cmap[k]]);
        h1[k] = b2f(ld[2 * LDW + cmap[k]]);
    }

    for (int m = 0; m < TT; m++) {
        int t = t0 + m;
        size_t rowp = (size_t)(b * LN_TOK + t) * GNN;
        float xpart = 0.f;
#pragma unroll
        for (int k = 0; k < 5; k++) {
            float cur = b2f(ld[(m + 3) * LDW + cmap[k]]);
            float conv = bias[k] + w3[k] * cur + w2[k] * h1[k] + w1[k] * h2[k] + w0[k] * h3[k];
            h3[k] = h2[k]; h2[k] = h1[k]; h1[k] = cur;
            float s = siluf_(conv);
            if (k < 4) xpart += s;
            else {
                u16 sb = f2b(s);
                if (tid < 128) { Bsh[rowp + tid] = sb; bcv[m][tid] = sb; }
                else           Csh[rowp + tid - 128] = sb;
            }
        }
        sv[m][tid] = xpart;
        if (tid < NHEADS) {
            float dtv = b2f(ld[(m + 3) * LDW + 1280 + tid]) + dtb;
            float dp = softplusf_(dtv);
            size_t idx = ((size_t)(b * NHEADS + tid)) * LN_TOK + t;
            dtp[idx] = dp;
            laa[idx] = negA * dp;
        }
    }
    __syncthreads();

    // xsh row-major
    for (int idx = tid; idx < TT * 128; idx += 256) {
        int m = idx >> 7, p = idx & 127;
        xsh[(size_t)(b * LN_TOK + t0 + m) * GNN + p] =
            f2b((sv[m][p] + sv[m][p + 128]) * 0.125f);
    }
    // XT / BT transposed (ushort8 stores along t)
    {
        int p = tid & 127, tg = tid >> 7;
        u16 ox[8], ob[8];
#pragma unroll
        for (int j = 0; j < 8; j++) {
            int m = tg * 8 + j;
            ox[j] = f2b((sv[m][p] + sv[m][p + 128]) * 0.125f);
            ob[j] = bcv[m][p];
        }
        size_t base = ((size_t)(b * GNN + p)) * LN_TOK + t0 + tg * 8;
        int4 vx = make_int4((u32)ox[0] | ((u32)ox[1] << 16), (u32)ox[2] | ((u32)ox[3] << 16),
                            (u32)ox[4] | ((u32)ox[5] << 16), (u32)ox[6] | ((u32)ox[7] << 16));
        int4 vb = make_int4((u32)ob[0] | ((u32)ob[1] << 16), (u32)ob[2] | ((u32)ob[3] << 16),
                            (u32)ob[4] | ((u32)ob[5] << 16), (u32)ob[6] | ((u32)ob[7] << 16));
        *(int4*)&XT[base] = vx;
        *(int4*)&BT[base] = vb;
    }
}

// ---------------- per-chunk inclusive prefix sum of log-decay ----------------
__global__ void k_prefix(const float* __restrict__ laa, float* __restrict__ gcum) {
    int blk = blockIdx.x;
    int bh = blk / NCHUNK, c = blk % NCHUNK;
    int tid = threadIdx.x;
    __shared__ float s[128];
    size_t base = (size_t)bh * LN_TOK + c * CHUNK;
    s[tid] = laa[base + tid];
    __syncthreads();
    for (int off = 1; off < 128; off <<= 1) {
        float v = (tid >= off) ? s[tid - off] : 0.f;
        __syncthreads();
        s[tid] += v;
        __syncthreads();
    }
    gcum[base + tid] = s[tid];
}

// ---------------- chunkM (MFMA): Mb[t][s] = mask*exp(g_t-g_s)*dt_s*(B'_s.C_t)
__global__ __launch_bounds__(256) void k_chunkM(const u16* __restrict__ Bsh,
                                                const u16* __restrict__ Csh,
                                                const float* __restrict__ scale,
                                                const float* __restrict__ gcum,
                                                const float* __restrict__ dtp,
                                                u16* __restrict__ Mb) {
    int blk = blockIdx.x;
    int c = blk & 31, h = (blk >> 5) & 7, b = blk >> 8;
    int t0 = c * CHUNK;
    __shared__ u16 As[128 * GPAD];
    __shared__ u16 Bs[128 * GPAD];
    __shared__ float g[128], dts[128], sc[128];
    int tid = threadIdx.x;
    int wave = tid >> 6, lane = tid & 63;
    int wm = wave >> 1, wn = wave & 1;
    int quad = lane >> 4, l16 = lane & 15;
    size_t bhbase = (size_t)(b * NHEADS + h) * LN_TOK + t0;
    if (tid < 128) {
        g[tid] = gcum[bhbase + tid];
        dts[tid] = dtp[bhbase + tid];
        sc[tid] = scale[h * GNN + tid];
    }
    __syncthreads();
    floatx4 acc[4][4] = {};
    size_t rbase = (size_t)(b * LN_TOK + t0) * GNN;
    for (int k0 = 0; k0 < 128; k0 += 64) {
#pragma unroll
        for (int p = 0; p < 4; p++) {
            int i = p * 256 + tid;
            int row = i >> 3, kk = (i & 7) << 3;
            int4 raw = *(const int4*)&Bsh[rbase + (size_t)row * GNN + k0 + kk];
            u16* rp = (u16*)&raw;
            u32 w[4];
#pragma unroll
            for (int q = 0; q < 4; q++) {
                u16 a  = f2b(b2f(rp[2 * q])     * sc[k0 + kk + 2 * q]);
                u16 bb = f2b(b2f(rp[2 * q + 1]) * sc[k0 + kk + 2 * q + 1]);
                w[q] = (u32)a | ((u32)bb << 16);
            }
            *(int4*)&As[row * GPAD + kk] = make_int4(w[0], w[1], w[2], w[3]);
            *(int4*)&Bs[row * GPAD + kk] = *(const int4*)&Csh[rbase + (size_t)row * GNN + k0 + kk];
        }
        __syncthreads();
#pragma unroll
        for (int ks = 0; ks < 64; ks += 32) {
            shortx8 af[4], bfr[4];
#pragma unroll
            for (int i = 0; i < 4; i++)
                af[i] = *(shortx8*)&As[(wm * 64 + i * 16 + l16) * GPAD + ks + (quad << 3)];
#pragma unroll
            for (int j = 0; j < 4; j++)
                bfr[j] = *(shortx8*)&Bs[(wn * 64 + j * 16 + l16) * GPAD + ks + (quad << 3)];
#pragma unroll
            for (int i = 0; i < 4; i++)
#pragma unroll
                for (int j = 0; j < 4; j++)
                    acc[i][j] = __builtin_amdgcn_mfma_f32_16x16x32_bf16(af[i], bfr[j], acc[i][j], 0, 0, 0);
        }
        __syncthreads();
    }
    size_t mb = (size_t)blk * (CHUNK * CHUNK);
#pragma unroll
    for (int i = 0; i < 4; i++) {
        int s0 = wm * 64 + i * 16 + quad * 4;
#pragma unroll
        for (int j = 0; j < 4; j++) {
            int t = wn * 64 + j * 16 + l16;
            u16 o[4];
#pragma unroll
            for (int r = 0; r < 4; r++) {
                int s = s0 + r;
                float v = (s <= t) ? acc[i][j][r] * __expf(g[t] - g[s]) * dts[s] : 0.f;
                o[r] = f2b(v);
            }
            u32 lo = (u32)o[0] | ((u32)o[1] << 16);
            u32 hi = (u32)o[2] | ((u32)o[3] << 16);
            *(uint2*)&Mb[mb + (size_t)t * CHUNK + s0] = make_uint2(lo, hi);
        }
    }
}

// ---------------- chunkS (MFMA): states[p][n] = sum_s XT[p][s]*BT[n][s]*sc*esc
__global__ __launch_bounds__(256) void k_chunkS(const u16* __restrict__ BT,
                                                const u16* __restrict__ XT,
                                                const float* __restrict__ scale,
                                                const float* __restrict__ gcum,
                                                const float* __restrict__ dtp,
                                                u16* __restrict__ states) {
    int blk = blockIdx.x;
    int c = blk & 31, h = (blk >> 5) & 7, b = blk >> 8;
    int t0 = c * CHUNK;
    __shared__ u16 As[128 * GPAD];
    __shared__ u16 Bs[128 * GPAD];
    __shared__ float esc[128], scl[128];
    int tid = threadIdx.x;
    int wave = tid >> 6, lane = tid & 63;
    int wm = wave >> 1, wn = wave & 1;
    int quad = lane >> 4, l16 = lane & 15;
    size_t bhbase = (size_t)(b * NHEADS + h) * LN_TOK + t0;
    if (tid < 128) {
        float gl = gcum[bhbase + 127];
        esc[tid] = __expf(gl - gcum[bhbase + tid]) * dtp[bhbase + tid];
        scl[tid] = scale[h * GNN + tid];
    }
    __syncthreads();
    floatx4 acc[4][4] = {};
    size_t tbase = (size_t)(b * GNN) * LN_TOK + t0;
    for (int k0 = 0; k0 < 128; k0 += 64) {
#pragma unroll
        for (int p = 0; p < 4; p++) {
            int i = p * 256 + tid;
            int row = i >> 3, kk = (i & 7) << 3;
            int4 raw = *(const int4*)&BT[tbase + (size_t)row * LN_TOK + k0 + kk];
            u16* rp = (u16*)&raw;
            float sr = scl[row];
            u32 w[4];
#pragma unroll
            for (int q = 0; q < 4; q++) {
                u16 a  = f2b(b2f(rp[2 * q])     * sr * esc[k0 + kk + 2 * q]);
                u16 bb = f2b(b2f(rp[2 * q + 1]) * sr * esc[k0 + kk + 2 * q + 1]);
                w[q] = (u32)a | ((u32)bb << 16);
            }
            *(int4*)&As[row * GPAD + kk] = make_int4(w[0], w[1], w[2], w[3]);
            *(int4*)&Bs[row * GPAD + kk] = *(const int4*)&XT[tbase + (size_t)row * LN_TOK + k0 + kk];
        }
        __syncthreads();
#pragma unroll
        for (int ks = 0; ks < 64; ks += 32) {
            shortx8 af[4], bfr[4];
#pragma unroll
            for (int i = 0; i < 4; i++)
                af[i] = *(shortx8*)&As[(wm * 64 + i * 16 + l16) * GPAD + ks + (quad << 3)];
#pragma unroll
            for (int j = 0; j < 4; j++)
                bfr[j] = *(shortx8*)&Bs[(wn * 64 + j * 16 + l16) * GPAD + ks + (quad << 3)];
#pragma unroll
            for (int i = 0; i < 4; i++)
#pragma unroll
                for (int j = 0; j < 4; j++)
                    acc[i][j] = __builtin_amdgcn_mfma_f32_16x16x32_bf16(af[i], bfr[j], acc[i][j], 0, 0, 0);
        }
        __syncthreads();
    }
    size_t sbase = (size_t)blk * 16384;
#pragma unroll
    for (int i = 0; i < 4; i++) {
        int n0 = wm * 64 + i * 16 + quad * 4;
#pragma unroll
        for (int j = 0; j < 4; j++) {
            int p = wn * 64 + j * 16 + l16;
            u16 o[4];
#pragma unroll
            for (int r = 0; r < 4; r++) o[r] = f2b(acc[i][j][r]);
            u32 lo = (u32)o[0] | ((u32)o[1] << 16);
            u32 hi = (u32)o[2] | ((u32)o[3] << 16);
            *(uint2*)&states[sbase + (size_t)p * CHUNK + n0] = make_uint2(lo, hi);
        }
    }
}

// ---------------- inter-chunk scan (in-place, bf16 storage) ------------------
__global__ void k_scan(u16* __restrict__ states, const float* __restrict__ gcum) {
    int idx = blockIdx.x * 256 + threadIdx.x;
    int bh = idx >> 14;
    int np = idx & 16383;
    float run = 0.f;
    size_t base = (size_t)bh * NCHUNK * 16384 + np;
    size_t gb = (size_t)bh * LN_TOK;
    for (int c = 0; c < NCHUNK; c++) {
        float G = __expf(gcum[gb + c * CHUNK + 127]);
        float l = b2f(states[base + (size_t)c * 16384]);
        states[base + (size_t)c * 16384] = f2b(run);
        run = G * run + l;
    }
}

// ---------------- chunkY (MFMA): y = eg[t]*C @ S0^T + Mb @ X^T (bf16 out) ----
__global__ __launch_bounds__(256) void k_chunkY(const u16* __restrict__ Csh,
                                                const u16* __restrict__ states,
                                                const u16* __restrict__ Mb,
                                                const u16* __restrict__ XT,
                                                const float* __restrict__ gcum,
                                                u16* __restrict__ y) {
    int blk = blockIdx.x;
    int c = blk & 31, h = (blk >> 5) & 7, b = blk >> 8;
    int t0 = c * CHUNK;
    __shared__ u16 As[128 * GPAD];
    __shared__ u16 Bs[128 * GPAD];
    __shared__ float eg[128];
    int tid = threadIdx.x;
    int wave = tid >> 6, lane = tid & 63;
    int wm = wave >> 1, wn = wave & 1;
    int quad = lane >> 4, l16 = lane & 15;
    size_t bhbase = (size_t)(b * NHEADS + h) * LN_TOK + t0;
    if (tid < 128) eg[tid] = __expf(gcum[bhbase + tid]);
    __syncthreads();
    floatx4 acc[4][4] = {};
    size_t crow = (size_t)(b * LN_TOK + t0) * GNN;
    size_t sbase = (size_t)blk * 16384;
    size_t mbase = (size_t)blk * 16384;
    size_t xtb = (size_t)(b * GNN) * LN_TOK + t0;
    // phase 1: K = n (eg[t]*Csh, states[p][n] bf16)
    for (int k0 = 0; k0 < 128; k0 += 64) {
#pragma unroll
        for (int p = 0; p < 4; p++) {
            int i = p * 256 + tid;
            int row = i >> 3, kk = (i & 7) << 3;
            int4 raw = *(const int4*)&Csh[crow + (size_t)row * GNN + k0 + kk];
            float e = eg[row];
            u16* rp = (u16*)&raw;
            u32 w[4];
#pragma unroll
            for (int q = 0; q < 4; q++) {
                u16 a  = f2b(b2f(rp[2 * q]) * e);
                u16 bb = f2b(b2f(rp[2 * q + 1]) * e);
                w[q] = (u32)a | ((u32)bb << 16);
            }
            *(int4*)&As[row * GPAD + kk] = make_int4(w[0], w[1], w[2], w[3]);
            *(int4*)&Bs[row * GPAD + kk] = *(const int4*)&states[sbase + (size_t)row * CHUNK + k0 + kk];
        }
        __syncthreads();
#pragma unroll
        for (int ks = 0; ks < 64; ks += 32) {
            shortx8 af[4], bfr[4];
#pragma unroll
            for (int i = 0; i < 4; i++)
                af[i] = *(shortx8*)&As[(wm * 64 + i * 16 + l16) * GPAD + ks + (quad << 3)];
#pragma unroll
            for (int j = 0; j < 4; j++)
                bfr[j] = *(shortx8*)&Bs[(wn * 64 + j * 16 + l16) * GPAD + ks + (quad << 3)];
#pragma unroll
            for (int i = 0; i < 4; i++)
#pragma unroll
                for (int j = 0; j < 4; j++)
                    acc[i][j] = __builtin_amdgcn_mfma_f32_16x16x32_bf16(af[i], bfr[j], acc[i][j], 0, 0, 0);
        }
        __syncthreads();
    }
    // phase 2: K = s (Mb[t][s], XT[p][s])
    for (int k0 = 0; k0 < 128; k0 += 64) {
#pragma unroll
        for (int p = 0; p < 4; p++) {
            int i = p * 256 + tid;
            int row = i >> 3, kk = (i & 7) << 3;
            *(int4*)&As[row * GPAD + kk] = *(const int4*)&Mb[mbase + (size_t)row * CHUNK + k0 + kk];
            *(int4*)&Bs[row * GPAD + kk] = *(const int4*)&XT[xtb + (size_t)row * LN_TOK + k0 + kk];
        }
        __syncthreads();
#pragma unroll
        for (int ks = 0; ks < 64; ks += 32) {
            shortx8 af[4], bfr[4];
#pragma unroll
            for (int i = 0; i < 4; i++)
                af[i] = *(shortx8*)&As[(wm * 64 + i * 16 + l16) * GPAD + ks + (quad << 3)];
#pragma unroll
            for (int j = 0; j < 4; j++)
                bfr[j] = *(shortx8*)&Bs[(wn * 64 + j * 16 + l16) * GPAD + ks + (quad << 3)];
#pragma unroll
            for (int i = 0; i < 4; i++)
#pragma unroll
                for (int j = 0; j < 4; j++)
                    acc[i][j] = __builtin_amdgcn_mfma_f32_16x16x32_bf16(af[i], bfr[j], acc[i][j], 0, 0, 0);
        }
        __syncthreads();
    }
#pragma unroll
    for (int i = 0; i < 4; i++) {
        int t = wm * 64 + i * 16 + quad * 4;
#pragma unroll
        for (int j = 0; j < 4; j++) {
            int p = wn * 64 + j * 16 + l16;
#pragma unroll
            for (int r = 0; r < 4; r++)
                y[((size_t)(b * LN_TOK + t0 + t + r)) * DINNER + h * GNN + p] = f2b(acc[i][j][r]);
        }
    }
}

// ---------------- gating + D*x + RMSNorm -> bf16 ybuf ------------------------
__global__ void k_gate(const u16* __restrict__ y, const u16* __restrict__ zxb,
                       const u16* __restrict__ xsh, const float* __restrict__ Dp,
                       const float* __restrict__ rw, u16* __restrict__ ybuf) {
    int row = blockIdx.x;
    int tid = threadIdx.x;
    size_t yb = (size_t)row * DINNER;
    size_t zb = (size_t)row * ZSTRIDE;
    size_t xb = (size_t)row * GNN;
    float yg[4];
    float ss = 0.f;
#pragma unroll
    for (int q = 0; q < 4; q++) {
        int k = tid * 4 + q;
        int h = k >> 7, p = k & 127;
        float z = b2f(zxb[zb + k]);
        float v = (b2f(y[yb + k]) + Dp[h] * b2f(xsh[xb + p])) * z * sigmoidf_(z);
        yg[q] = v;
        ss += v * v;
    }
    __shared__ float red[256];
    red[tid] = ss;
    __syncthreads();
    for (int off = 128; off > 0; off >>= 1) {
        if (tid < off) red[tid] += red[tid + off];
        __syncthreads();
    }
    float scale = rsqrtf(red[0] * (1.f / DINNER) + EPSF);
#pragma unroll
    for (int q = 0; q < 4; q++) {
        int k = tid * 4 + q;
        ybuf[yb + k] = f2b(yg[q] * scale * rw[k]);
    }
}

extern "C" void kernel_launch(void* const* d_in, const int* in_sizes, int n_in,
                              void* d_out, int out_size, void* d_ws, size_t ws_size,
                              hipStream_t stream) {
    (void)in_sizes; (void)n_in; (void)out_size; (void)ws_size;
    const float* u        = (const float*)d_in[0];
    const float* ln_gamma = (const float*)d_in[1];
    const float* ln_beta  = (const float*)d_in[2];
    const float* W_in     = (const float*)d_in[3];
    const float* conv_w   = (const float*)d_in[4];
    const float* conv_b   = (const float*)d_in[5];
    const float* dt_bias  = (const float*)d_in[6];
    const float* A_log    = (const float*)d_in[7];
    const float* D_param  = (const float*)d_in[8];
    const float* B_scale  = (const float*)d_in[9];
    const float* rms_w    = (const float*)d_in[10];
    const float* W_out    = (const float*)d_in[11];
    float* out = (float*)d_out;

    char* ws = (char*)d_ws;
    u16*   xn_b   = (u16*)ws;                 ws += (size_t)NROWS * DMODEL * 2;
    u16*   Wt     = (u16*)ws;                 ws += (size_t)ZSTRIDE * DMODEL * 2;
    u16*   Wot    = (u16*)ws;                 ws += (size_t)DMODEL * DINNER * 2;
    u16*   zxb    = (u16*)ws;                 ws += (size_t)NROWS * ZSTRIDE * 2;
    u16*   xsh    = (u16*)ws;                 ws += (size_t)NROWS * GNN * 2;
    u16*   Bsh    = (u16*)ws;                 ws += (size_t)NROWS * GNN * 2;
    u16*   Csh    = (u16*)ws;                 ws += (size_t)NROWS * GNN * 2;
    u16*   XT     = (u16*)ws;                 ws += (size_t)NB * GNN * LN_TOK * 2;
    u16*   BT     = (u16*)ws;                 ws += (size_t)NB * GNN * LN_TOK * 2;
    float* dtp    = (float*)ws;               ws += (size_t)NB * NHEADS * LN_TOK * 4;
    float* laa    = (float*)ws;               ws += (size_t)NB * NHEADS * LN_TOK * 4;
    float* gcum   = (float*)ws;               ws += (size_t)NB * NHEADS * LN_TOK * 4;
    u16*   Mb     = (u16*)ws;                 ws += (size_t)512 * 16384 * 2;
    u16*   states = (u16*)ws;                 ws += (size_t)512 * 16384 * 2;
    u16*   ybig   = (u16*)ws;                 ws += (size_t)NROWS * DINNER * 2;
    u16*   ybuf   = Mb;  // reuse (Mb dead after k_chunkY)

    k_ln<<<NROWS, 256, 0, stream>>>(u, ln_gamma, ln_beta, xn_b);

    k_tcast<<<dim3(ZSTRIDE / 64, DMODEL / 64), 256, 0, stream>>>(W_in, Wt, DMODEL, DPROJ, ZSTRIDE);
    k_tcast<<<dim3(DMODEL / 64, DINNER / 64), 256, 0, stream>>>(W_out, Wot, DINNER, DMODEL, DMODEL);

    k_gemm_bf<<<dim3(ZSTRIDE / 128, NROWS / 128), 256, 0, stream>>>(xn_b, Wt, zxb, DMODEL, ZSTRIDE);

    k_conv<<<NROWS / TT, 256, 0, stream>>>(zxb, conv_w, conv_b, dt_bias, A_log,
                                           xsh, Bsh, Csh, XT, BT, dtp, laa);

    k_prefix<<<NB * NHEADS * NCHUNK, 128, 0, stream>>>(laa, gcum);

    k_chunkM<<<NB * NHEADS * NCHUNK, 256, 0, stream>>>(Bsh, Csh, B_scale, gcum, dtp, Mb);

    k_chunkS<<<NB * NHEADS * NCHUNK, 256, 0, stream>>>(BT, XT, B_scale, gcum, dtp, states);

    k_scan<<<(NB * NHEADS * 16384) / 256, 256, 0, stream>>>(states, gcum);

    k_chunkY<<<NB * NHEADS * NCHUNK, 256, 0, stream>>>(Csh, states, Mb, XT, gcum, ybig);

    k_gate<<<NROWS, 256, 0, stream>>>(ybig, zxb, xsh, D_param, rms_w, ybuf);

    k_gemm2<<<dim3(DMODEL / 64, NROWS / 128), 256, 0, stream>>>(ybuf, Wot, out, DINNER, DMODEL, u);
}